// Round 10
// baseline (1486.255 us; speedup 1.0000x reference)
//
#include <hip/hip_runtime.h>
#include <math.h>

#define B 4
#define T 512
#define D 256
#define H 1024
#define NH 8
#define V 32000
#define BT (B*T)
#define LE 2
#define LD 2
#define DIM 1024  // expanded width = 4*D

typedef __attribute__((ext_vector_type(8))) short s16x8;
typedef __attribute__((ext_vector_type(4))) float f32x4;
typedef __attribute__((address_space(3))) void lds_void;
typedef const __attribute__((address_space(1))) void g_void;

__device__ __forceinline__ ushort f2bf(float x) {
  uint u = __float_as_uint(x);
  return (ushort)((u + 0x7fffu + ((u >> 16) & 1u)) >> 16);
}

#define QSCALE 0.08838834764831845f  // 1/sqrt(128), baked into Q at QKV epilogue

// ---------------------------------------------------------------------------
// ONE launch: all weight expansion + fc convert + BOTH embeds
#define A_CNT  1572864
#define F_CNT  2097152
#define FC_CNT 2048000
#define EMB_CNT (2 * BT * 256)
#define MEGA_TOT (A_CNT + F_CNT + FC_CNT + EMB_CNT)
#define WSTEP  1048576   // DIM*DIM elems
#define FFW    4194304   // 4H*DIM elems

__device__ __forceinline__ void qexpand_write(
    const float* __restrict__ src, ushort* __restrict__ dst,
    int o, int d, int Din, int P) {
  float w0 = src[(size_t)o * Din + d];
  float w1 = src[P + (size_t)o * Din + d];
  float w2 = src[2 * (size_t)P + (size_t)o * Din + d];
  float w3 = src[3 * (size_t)P + (size_t)o * Din + d];
  int K4 = Din * 4;
  size_t rbase = (size_t)(o * 4) * K4 + d * 4;
  *(ushort4*)(dst + rbase)          = make_ushort4(f2bf(w0), f2bf(-w1), f2bf(-w2), f2bf(-w3));
  *(ushort4*)(dst + rbase + K4)     = make_ushort4(f2bf(w1), f2bf(w0),  f2bf(w3),  f2bf(-w2));
  *(ushort4*)(dst + rbase + 2 * K4) = make_ushort4(f2bf(w2), f2bf(-w3), f2bf(w0),  f2bf(w1));
  *(ushort4*)(dst + rbase + 3 * K4) = make_ushort4(f2bf(w3), f2bf(w2),  f2bf(-w1), f2bf(w0));
}

__global__ __launch_bounds__(256) void mega_expand_kernel(
    const float* __restrict__ encA, const float* __restrict__ decSA,
    const float* __restrict__ decCA,
    const float* __restrict__ eW1, const float* __restrict__ eW2,
    const float* __restrict__ dW1, const float* __restrict__ dW2,
    const float* __restrict__ fcW,
    ushort* __restrict__ WA, ushort* __restrict__ WF, ushort* __restrict__ Wfc,
    const int* __restrict__ srcIds, const int* __restrict__ tgtIds,
    const float* __restrict__ emb,
    float* __restrict__ xsrc, ushort* __restrict__ xbfs,
    float* __restrict__ xtgt, ushort* __restrict__ xbft) {
  int gid = blockIdx.x * 256 + threadIdx.x;
  if (gid < A_CNT) {
    int u = gid >> 18;
    int p = (gid >> 16) & 3;
    int rem = gid & 65535;
    int o = rem >> 8, d = rem & 255;
    const float* base = (u < 2) ? encA + (size_t)u * 1048576
                      : (u < 4) ? decSA + (size_t)(u - 2) * 1048576
                                : decCA + (size_t)(u - 4) * 1048576;
    qexpand_write(base + (size_t)p * 262144,
                  WA + ((size_t)u * 4 + p) * WSTEP, o, d, 256, 65536);
  } else if (gid < A_CNT + F_CNT) {
    int idx = gid - A_CNT;
    int layer = idx >> 19;
    int w12 = (idx >> 18) & 1;
    int rem = idx & 262143;
    const float* w1b = (layer < 2) ? eW1 + (size_t)layer * 1048576
                                   : dW1 + (size_t)(layer - 2) * 1048576;
    const float* w2b = (layer < 2) ? eW2 + (size_t)layer * 1048576
                                   : dW2 + (size_t)(layer - 2) * 1048576;
    ushort* dst = WF + (size_t)layer * 2 * FFW + (size_t)w12 * FFW;
    if (w12 == 0) {
      int o = rem >> 8, d = rem & 255;
      qexpand_write(w1b, dst, o, d, 256, 262144);
    } else {
      int o = rem >> 10, d = rem & 1023;
      qexpand_write(w2b, dst, o, d, 1024, 262144);
    }
  } else if (gid < A_CNT + F_CNT + FC_CNT) {
    int idx = gid - A_CNT - F_CNT;
    float4 v = ((const float4*)fcW)[idx];
    ((ushort4*)Wfc)[idx] = make_ushort4(f2bf(v.x), f2bf(v.y), f2bf(v.z), f2bf(v.w));
  } else if (gid < MEGA_TOT) {
    int idx = gid - A_CNT - F_CNT - FC_CNT;
    int g = idx >> 8, d = idx & 255;
    int isTgt = g >= BT;
    int bt = isTgt ? g - BT : g;
    int id = isTgt ? tgtIds[bt] : srcIds[bt];
    float* out = isTgt ? xtgt : xsrc;
    ushort* outbf = isTgt ? xbft : xbfs;
    int t = bt % T;
    size_t VD = (size_t)V * D;
    float scale = powf(10000.f, -(float)d / (float)D);
    float r = emb[(size_t)id * D + d];
    float i = emb[VD + (size_t)id * D + d] * scale;
    float j = emb[2 * VD + (size_t)id * D + d] * scale;
    float k = emb[3 * VD + (size_t)id * D + d] * scale;
    float n = sqrtf(r * r + i * i + j * j + k * k + 1e-6f);
    float ang;
    if (d < D / 2) {
      float inv = powf(10000.f, -(float)(2 * d) / (float)D);
      ang = sinf((float)t * inv);
    } else {
      float inv = powf(10000.f, -(float)(2 * (d - D / 2)) / (float)D);
      ang = cosf((float)t * inv);
    }
    float s = ang / n;
    size_t base = (size_t)bt * DIM + d * 4;
    float4 q = make_float4(r * s, i * s, j * s, k * s);
    *(float4*)(out + base) = q;
    *(ushort4*)(outbf + base) = make_ushort4(f2bf(q.x), f2bf(q.y), f2bf(q.z), f2bf(q.w));
  }
}

// ---------------------------------------------------------------------------
// Unit-routed GEMM params (shared by both GEMM kernels)
struct GP {
  const ushort* A; const ushort* Aalt; int altStart;
  const ushort* Bt; const float* bias; void* Cv;
  ushort* qo; ushort* ko; ushort* vo;
  float* xres; ushort* xbf; const float* gg; const float* bb;
  const float* modb; ushort* realout;
};

// ---------------------------------------------------------------------------
// 2-WAVE high-ILP GEMM: 128 threads, 128x128 tile, per-wave 64x128 (acc 4x8),
// 32 MFMA : 12 ds_read_b128 per K-step (vs 16:8 in the 4-wave core).
// BK=32 double-buffer, 32 KB LDS, stage(t+1)-before-compute(t).
// OMODE 0: f32+bias. OMODE 3: QKV epilogue (Q pre-scaled by QSCALE).
// OMODE 5: +modrelu -> bf16.
template <int OMODE>
__global__ __launch_bounds__(128, 2) void gemm2w_kernel(
    GP u0, GP u1, int nunits, int N, int K) {
  __shared__ ushort As[2][128 * 32];
  __shared__ ushort Bs[2][128 * 32];
  const int tid = threadIdx.x;
  const int w = tid >> 6, l = tid & 63;
  const int nwg = gridDim.x;
  const int qq = nwg >> 3, rr = nwg & 7;
  const int xcd = blockIdx.x & 7, pos = blockIdx.x >> 3;
  const int wg = (xcd < rr ? xcd * (qq + 1) : rr * (qq + 1) + (xcd - rr) * qq) + pos;
  const int uwg = nwg / nunits;
  const int unit = wg / uwg;
  const int wgl = wg - unit * uwg;
  GP U = unit ? u1 : u0;
  const int nbx = N >> 7;
  const int nby = uwg / nbx;
  const int m0 = (wgl % nby) * 128, n0 = (wgl / nby) * 128;
  const ushort* Ap = (U.altStart && n0 >= U.altStart) ? U.Aalt : U.A;
  const ushort* Btp = U.Bt;
  const int lr = l & 15, lg = l >> 4;
  f32x4 acc[4][8] = {};
  const int NT = K >> 5;

  auto stage = [&](int t, int buf) {
    int k0 = t << 5;
#pragma unroll
    for (int s = 0; s < 4; ++s) {
      int f = (s * 128 + tid) * 16;
      int row = f >> 6, cb = (f & 63) >> 1;
      __builtin_amdgcn_global_load_lds(
          (g_void*)(Ap + (size_t)(m0 + row) * K + k0 + cb),
          (lds_void*)((char*)&As[buf][0] + f), 16, 0, 0);
    }
#pragma unroll
    for (int s = 0; s < 4; ++s) {
      int f = (s * 128 + tid) * 16;
      int row = f >> 6, cb = (f & 63) >> 1;
      __builtin_amdgcn_global_load_lds(
          (g_void*)(Btp + (size_t)(n0 + row) * K + k0 + cb),
          (lds_void*)((char*)&Bs[buf][0] + f), 16, 0, 0);
    }
  };

  stage(0, 0);
  __syncthreads();
  int cur = 0;
  for (int t = 0; t < NT; ++t) {
    if (t + 1 < NT) stage(t + 1, cur ^ 1);
    s16x8 af[4], bfr[8];
#pragma unroll
    for (int mi = 0; mi < 4; ++mi)
      af[mi] = *(const s16x8*)(&As[cur][0] + (w * 64 + mi * 16 + lr) * 32 + lg * 8);
#pragma unroll
    for (int ni = 0; ni < 8; ++ni)
      bfr[ni] = *(const s16x8*)(&Bs[cur][0] + (ni * 16 + lr) * 32 + lg * 8);
    __builtin_amdgcn_s_setprio(1);
#pragma unroll
    for (int mi = 0; mi < 4; ++mi)
#pragma unroll
      for (int ni = 0; ni < 8; ++ni)
        acc[mi][ni] = __builtin_amdgcn_mfma_f32_16x16x32_bf16(af[mi], bfr[ni], acc[mi][ni], 0, 0, 0);
    __builtin_amdgcn_s_setprio(0);
    __syncthreads();
    cur ^= 1;
  }

#pragma unroll
  for (int mi = 0; mi < 4; ++mi) {
#pragma unroll
    for (int ni = 0; ni < 8; ++ni) {
      int row = m0 + w * 64 + mi * 16 + lg * 4;
      int col = n0 + ni * 16 + lr;
      f32x4 v = acc[mi][ni];
      if constexpr (OMODE == 0) {
        float bv = U.bias ? U.bias[col] : 0.f;
        float* C = (float*)U.Cv;
#pragma unroll
        for (int r = 0; r < 4; ++r)
          C[(size_t)(row + r) * N + col] = v[r] + bv;
      } else if constexpr (OMODE == 3) {
        float bv = U.bias[col];
        if (col < 2048) {
          ushort* dst = (col < DIM) ? U.qo : U.ko;
          float sc = (col < DIM) ? QSCALE : 1.f;
          int c = col & (DIM - 1);
#pragma unroll
          for (int r = 0; r < 4; ++r)
            dst[(size_t)(row + r) * DIM + c] = f2bf((v[r] + bv) * sc);
        } else {
          int c = col - 2048;
          ushort4 o4 = make_ushort4(f2bf(v[0] + bv), f2bf(v[1] + bv),
                                    f2bf(v[2] + bv), f2bf(v[3] + bv));
          *(ushort4*)&U.vo[((size_t)((row >> 9) << 10) + c) * T + (row & 511)] = o4;
        }
      } else {  // OMODE 5: modrelu
        float bv = U.bias[col];
        float mb = U.modb[col >> 2];
        ushort* C = (ushort*)U.Cv;
#pragma unroll
        for (int r = 0; r < 4; ++r) {
          float val = v[r] + bv;
          float sq = val * val;
          sq += __shfl_xor(sq, 1);
          sq += __shfl_xor(sq, 2);
          float norm = sqrtf(sq);
          float scale = fmaxf(norm + mb, 0.f) / (norm + 1e-6f);
          C[(size_t)(row + r) * N + col] = f2bf(val * scale);
        }
      }
    }
  }
}

// ---------------------------------------------------------------------------
// 4-wave TM=64 GEMM for N=1024 chains (OP, FF2): OMODE 4 = +resid+qnorm(+real)
template <int OMODE, int TM>
__global__ __launch_bounds__(256, 4) void gemm_bf16_kernel(
    GP u0, GP u1, int nunits, int N, int K) {
  __shared__ ushort As[2][TM * 32];
  __shared__ ushort Bs[2][128 * 32];
  const int tid = threadIdx.x;
  const int w = tid >> 6, l = tid & 63;
  const int nwg = gridDim.x;
  const int qq = nwg >> 3, rr = nwg & 7;
  const int xcd = blockIdx.x & 7, pos = blockIdx.x >> 3;
  const int wg = (xcd < rr ? xcd * (qq + 1) : rr * (qq + 1) + (xcd - rr) * qq) + pos;
  const int uwg = nwg / nunits;
  const int unit = wg / uwg;
  const int wgl = wg - unit * uwg;
  GP U = unit ? u1 : u0;
  const int nbx = N >> 7;
  const int nby = uwg / nbx;
  const int m0 = (wgl % nby) * TM, n0 = (wgl / nby) * 128;
  const int lr = l & 15, lg = l >> 4;
  constexpr int NR = (TM == 128) ? 4 : 2;
  const int wm = (TM == 128) ? (w >> 1) : 0;
  const int wn = (TM == 128) ? (w & 1) : w;
  const int wcol = wn * (NR * 16);
  f32x4 acc[4][NR] = {};
  const int NT = K >> 5;

  auto stage = [&](int t, int buf) {
    int k0 = t << 5;
#pragma unroll
    for (int s = 0; s < TM / 64; ++s) {
      int fb = (w * (TM / 64) + s) * 1024;
      int f = fb + l * 16;
      int row = f >> 6, cb = (f & 63) >> 1;
      __builtin_amdgcn_global_load_lds(
          (g_void*)(U.A + (size_t)(m0 + row) * K + k0 + cb),
          (lds_void*)((char*)&As[buf][0] + fb), 16, 0, 0);
    }
#pragma unroll
    for (int s = 0; s < 2; ++s) {
      int fb = (w * 2 + s) * 1024;
      int f = fb + l * 16;
      int row = f >> 6, cb = (f & 63) >> 1;
      __builtin_amdgcn_global_load_lds(
          (g_void*)(U.Bt + (size_t)(n0 + row) * K + k0 + cb),
          (lds_void*)((char*)&Bs[buf][0] + fb), 16, 0, 0);
    }
  };

  stage(0, 0);
  __syncthreads();
  int cur = 0;
  for (int t = 0; t < NT; ++t) {
    if (t + 1 < NT) stage(t + 1, cur ^ 1);
    s16x8 af[4], bfr[NR];
#pragma unroll
    for (int mi = 0; mi < 4; ++mi)
      af[mi] = *(const s16x8*)(&As[cur][0] + (wm * 64 + mi * 16 + lr) * 32 + lg * 8);
#pragma unroll
    for (int ni = 0; ni < NR; ++ni)
      bfr[ni] = *(const s16x8*)(&Bs[cur][0] + (wcol + ni * 16 + lr) * 32 + lg * 8);
    __builtin_amdgcn_s_setprio(1);
#pragma unroll
    for (int mi = 0; mi < 4; ++mi)
#pragma unroll
      for (int ni = 0; ni < NR; ++ni)
        acc[mi][ni] = __builtin_amdgcn_mfma_f32_16x16x32_bf16(af[mi], bfr[ni], acc[mi][ni], 0, 0, 0);
    __builtin_amdgcn_s_setprio(0);
    __syncthreads();
    cur ^= 1;
  }

#pragma unroll
  for (int mi = 0; mi < 4; ++mi) {
#pragma unroll
    for (int ni = 0; ni < NR; ++ni) {
      int row = m0 + wm * 64 + mi * 16 + lg * 4;
      int col = n0 + wcol + ni * 16 + lr;
      f32x4 v = acc[mi][ni];
      if constexpr (OMODE == 4) {
        float bv = U.bias[col];
        float gv = U.gg[col], bev = U.bb[col];
#pragma unroll
        for (int r = 0; r < 4; ++r) {
          float val = v[r] + bv + U.xres[(size_t)(row + r) * DIM + col];
          float sq = val * val;
          sq += __shfl_xor(sq, 1);
          sq += __shfl_xor(sq, 2);
          float invn = rsqrtf(sq + 1e-6f);
          float res = gv * (val * invn) + bev;
          U.xres[(size_t)(row + r) * DIM + col] = res;
          U.xbf[(size_t)(row + r) * DIM + col] = f2bf(res);
          if (U.realout) {
            float rsq = res * res;
            rsq += __shfl_xor(rsq, 1);
            rsq += __shfl_xor(rsq, 2);
            if ((col & 3) == 0)
              U.realout[(size_t)(row + r) * D + (col >> 2)] = f2bf(sqrtf(rsq));
          }
        }
      }
    }
  }
}

// ---------------------------------------------------------------------------
// fused flash attention, head-dim 128. grid (T/64, NH, B*npair), 4 waves.
// Q pre-scaled in QKV epilogue. Defer-max (THR=8) skips O-rescale.
__global__ __launch_bounds__(256) void fused_attn_kernel(
    const ushort* __restrict__ qb, const ushort* __restrict__ kb,
    const ushort* __restrict__ vT, ushort* __restrict__ outA,
    int c0, int c1) {
  __shared__ ushort Ks[2][64 * 128];
  __shared__ ushort Vs[2][128 * 64];
  __shared__ ushort Pst[4][1024];
  const int tid = threadIdx.x;
  const int wq = tid >> 6, l = tid & 63;
  const int lr = l & 15, lg = l >> 4;
  const int h = blockIdx.y;
  const int u = blockIdx.z >> 2, b = blockIdx.z & 3;
  const size_t uoff = (size_t)u * ((size_t)BT * DIM);
  const int causal = u ? c1 : c0;
  const int q0 = blockIdx.x * 64 + wq * 16;
  const size_t bT = (size_t)b * T;
  const int hc = h * 128;
  const size_t vrow0 = (size_t)(b * NH + h) * 128;
  const ushort* qbu = qb + uoff;
  const ushort* kbu = kb + uoff;
  const ushort* vTu = vT + uoff;
  ushort* outu = outA + uoff;
  s16x8 qf[4];
#pragma unroll
  for (int ks = 0; ks < 4; ++ks)
    qf[ks] = *(const s16x8*)(qbu + (bT + q0 + lr) * DIM + hc + ks * 32 + lg * 8);
  f32x4 O[8] = {};
  float m[4] = {-3e38f, -3e38f, -3e38f, -3e38f};
  float lac[4] = {0.f, 0.f, 0.f, 0.f};
  const int kend = causal ? (blockIdx.x + 1) * 64 : T;
  const int ntile = kend >> 6;

  auto stageKV = [&](int tile, int buf) {
    int kv0 = tile << 6;
#pragma unroll
    for (int s = 0; s < 4; ++s) {
      int f = s * 4096 + tid * 16;
      int row = f >> 8, g = (f >> 4) & 15;
      int gs = g ^ (row & 7);
      __builtin_amdgcn_global_load_lds(
          (g_void*)(kbu + (bT + kv0 + row) * DIM + hc + gs * 8),
          (lds_void*)((char*)&Ks[buf][0] + f), 16, 0, 0);
    }
#pragma unroll
    for (int s = 0; s < 4; ++s) {
      int f = s * 4096 + tid * 16;
      int row = f >> 7, g = (f >> 4) & 7;
      int gs = g ^ (row & 7);
      __builtin_amdgcn_global_load_lds(
          (g_void*)(vTu + (vrow0 + row) * T + kv0 + gs * 8),
          (lds_void*)((char*)&Vs[buf][0] + f), 16, 0, 0);
    }
  };

  stageKV(0, 0);
  __syncthreads();
  int cur = 0;
  for (int tile = 0; tile < ntile; ++tile) {
    const int kv0 = tile << 6;
    if (tile + 1 < ntile) stageKV(tile + 1, cur ^ 1);
    f32x4 s[4] = {};
#pragma unroll
    for (int ks = 0; ks < 4; ++ks) {
      s16x8 kf[4];
#pragma unroll
      for (int ni = 0; ni < 4; ++ni) {
        int row = ni * 16 + lr;
        int g = (ks * 4 + lg) ^ (row & 7);
        kf[ni] = *(const s16x8*)(&Ks[cur][0] + row * 128 + g * 8);
      }
#pragma unroll
      for (int ni = 0; ni < 4; ++ni)
        s[ni] = __builtin_amdgcn_mfma_f32_16x16x32_bf16(qf[ks], kf[ni], s[ni], 0, 0, 0);
    }
    const bool domask = causal && (kv0 + 63 > q0);
#pragma unroll
    for (int r = 0; r < 4; ++r) {
      const int qrow = q0 + lg * 4 + r;
      float mx = -3e38f;
#pragma unroll
      for (int ni = 0; ni < 4; ++ni) {
        float v = s[ni][r];
        if (domask && (kv0 + ni * 16 + lr > qrow)) v = -3e38f;
        s[ni][r] = v;
        mx = fmaxf(mx, v);
      }
#pragma unroll
      for (int dd = 1; dd < 16; dd <<= 1) mx = fmaxf(mx, __shfl_xor(mx, dd));
      // defer-max: only rescale when some row's max grew past THR=8
      if (__ballot(mx > m[r] + 8.f)) {
        float mn = fmaxf(m[r], mx);
        float alpha = __expf(m[r] - mn);
        m[r] = mn;
        lac[r] *= alpha;
#pragma unroll
        for (int dni = 0; dni < 8; ++dni) O[dni][r] *= alpha;
      }
      float ps = 0.f;
#pragma unroll
      for (int ni = 0; ni < 4; ++ni) {
        float p = __expf(s[ni][r] - m[r]);
        s[ni][r] = p;
        ps += p;
      }
#pragma unroll
      for (int dd = 1; dd < 16; dd <<= 1) ps += __shfl_xor(ps, dd);
      lac[r] += ps;
      const int qloc = lg * 4 + r;
      const int sw = (qloc & 7) << 3;
#pragma unroll
      for (int ni = 0; ni < 4; ++ni)
        Pst[wq][qloc * 64 + ((ni * 16 + lr) ^ sw)] = f2bf(s[ni][r]);
    }
    asm volatile("s_waitcnt lgkmcnt(0)" ::: "memory");
    __builtin_amdgcn_sched_barrier(0);
#pragma unroll
    for (int ks2 = 0; ks2 < 2; ++ks2) {
      s16x8 pa = *(const s16x8*)&Pst[wq][lr * 64 + ((ks2 * 32 + lg * 8) ^ ((lr & 7) << 3))];
#pragma unroll
      for (int dni = 0; dni < 8; ++dni) {
        int row = dni * 16 + lr;
        int g = (ks2 * 4 + lg) ^ (row & 7);
        s16x8 vf = *(const s16x8*)(&Vs[cur][0] + row * 64 + g * 8);
        O[dni] = __builtin_amdgcn_mfma_f32_16x16x32_bf16(pa, vf, O[dni], 0, 0, 0);
      }
    }
    __syncthreads();
    cur ^= 1;
  }
#pragma unroll
  for (int r = 0; r < 4; ++r) {
    float inv = 1.f / lac[r];
    const size_t row = bT + q0 + lg * 4 + r;
#pragma unroll
    for (int dni = 0; dni < 8; ++dni)
      outu[row * DIM + hc + dni * 16 + lr] = f2bf(O[dni][r] * inv);
  }
}

// ---------------------------------------------------------------------------
extern "C" void kernel_launch(void* const* d_in, const int* in_sizes, int n_in,
                              void* d_out, int out_size, void* d_ws, size_t ws_size,
                              hipStream_t stream) {
  const int*   src        = (const int*)d_in[0];
  const int*   tgt        = (const int*)d_in[1];
  const float* emb        = (const float*)d_in[3];
  const float* enc_attn_W = (const float*)d_in[4];
  const float* enc_attn_b = (const float*)d_in[5];
  const float* enc_norm_g = (const float*)d_in[6];
  const float* enc_norm_b = (const float*)d_in[7];
  const float* enc_ff_W1  = (const float*)d_in[8];
  const float* enc_ff_b1  = (const float*)d_in[9];
  const float* enc_ff_mod = (const float*)d_in[10];
  const float* enc_ff_W2  = (const float*)d_in[11];
  const float* enc_ff_b2  = (const float*)d_in[12];
  const float* dec_sa_W   = (const float*)d_in[13];
  const float* dec_sa_b   = (const float*)d_in[14];
  const float* dec_ca_W   = (const float*)d_in[15];
  const float* dec_ca_b   = (const float*)d_in[16];
  const float* dec_norm_g = (const float*)d_in[17];
  const float* dec_norm_b = (const float*)d_in[18];
  const float* dec_ff_W1  = (const float*)d_in[19];
  const float* dec_ff_b1  = (const float*)d_in[20];
  const float* dec_ff_mod = (const float*)d_in[21];
  const float* dec_ff_W2  = (const float*)d_in[22];
  const float* dec_ff_b2  = (const float*)d_in[23];
  const float* fc_W       = (const float*)d_in[24];
  const float* fc_b       = (const float*)d_in[25];
  float* out = (float*)d_out;

  const size_t USZ = (size_t)BT * DIM;
  float* ws    = (float*)d_ws;
  float* xsrc  = ws;
  float* xtgt  = xsrc + USZ;
  ushort* xbf_src = (ushort*)(xtgt + USZ);
  ushort* xbf_tgt = xbf_src + USZ;
  ushort* aobf    = xbf_tgt + USZ;      // 2 units
  ushort* qb      = aobf + 2 * USZ;     // 2 units
  ushort* kb      = qb + 2 * USZ;       // 2 units
  ushort* vTb     = kb + 2 * USZ;       // 2 units
  ushort* hbf     = vTb + 2 * USZ;      // BT*4096
  ushort* realbf  = hbf + (size_t)BT * H * 4;
  ushort* WA      = realbf + (size_t)BT * D;      // 24 * WSTEP
  ushort* WF      = WA + (size_t)6 * 4 * WSTEP;   // 8 * FFW
  ushort* Wfc     = WF + (size_t)4 * 2 * FFW;     // V*D

  mega_expand_kernel<<<(MEGA_TOT + 255) / 256, 256, 0, stream>>>(
      enc_attn_W, dec_sa_W, dec_ca_W,
      enc_ff_W1, enc_ff_W2, dec_ff_W1, dec_ff_W2, fc_W, WA, WF, Wfc,
      src, tgt, emb, xsrc, xbf_src, xtgt, xbf_tgt);

  GP Z{};

  auto mkQKV = [&](const ushort* Abf, const ushort* Wu, const float* bb, int u) {
    GP g = Z;
    g.A = Abf; g.Bt = Wu; g.bias = bb;
    g.qo = qb + u * USZ; g.ko = kb + u * USZ; g.vo = vTb + u * USZ;
    return g;
  };
  auto mkOP = [&](int u, const ushort* Wu3, const float* bb, float* xres,
                  ushort* xbf, const float* gg, const float* nb, ushort* realo) {
    GP g = Z;
    g.A = aobf + u * USZ; g.Bt = Wu3; g.bias = bb;
    g.xres = xres; g.xbf = xbf; g.gg = gg; g.bb = nb; g.realout = realo;
    return g;
  };

  auto qkv1 = [&](GP g) {
    gemm2w_kernel<3><<<384, 128, 0, stream>>>(g, g, 1, 3 * DIM, DIM);
  };
  auto qkv2 = [&](GP g0, GP g1) {
    gemm2w_kernel<3><<<768, 128, 0, stream>>>(g0, g1, 2, 3 * DIM, DIM);
  };
  auto op1 = [&](GP g) {
    gemm_bf16_kernel<4, 64><<<256, 256, 0, stream>>>(g, g, 1, DIM, DIM);
  };
  auto op2 = [&](GP g0, GP g1) {
    gemm_bf16_kernel<4, 64><<<512, 256, 0, stream>>>(g0, g1, 2, DIM, DIM);
  };
  auto attn1 = [&](int causal) {
    fused_attn_kernel<<<dim3(T / 64, NH, B), 256, 0, stream>>>(
        qb, kb, vTb, aobf, causal, causal);
  };
  auto ffpair = [&](const ushort* xbf, int layer, const float* b1,
                    const float* mod, const float* b2, float* xres,
                    ushort* xbfo, const float* gg, const float* nb,
                    ushort* realo) {
    const ushort* Wf = WF + (size_t)layer * 2 * FFW;
    GP g1 = Z;
    g1.A = xbf; g1.Bt = Wf; g1.bias = b1; g1.Cv = hbf; g1.modb = mod;
    gemm2w_kernel<5><<<512, 128, 0, stream>>>(g1, g1, 1, 4 * H, DIM);
    GP g2 = Z;
    g2.A = hbf; g2.Bt = Wf + FFW; g2.bias = b2;
    g2.xres = xres; g2.xbf = xbfo; g2.gg = gg; g2.bb = nb; g2.realout = realo;
    gemm_bf16_kernel<4, 64><<<256, 256, 0, stream>>>(g2, g2, 1, DIM, 4 * H);
  };

  // ---- enc.l0 ∥ dec.sa0 : merged QKV / attn / out-proj
  {
    GP e = mkQKV(xbf_src, WA + (size_t)(0 * 4) * WSTEP, enc_attn_b, 0);
    GP d = mkQKV(xbf_tgt, WA + (size_t)(2 * 4) * WSTEP, dec_sa_b, 1);
    qkv2(e, d);
    fused_attn_kernel<<<dim3(T / 64, NH, 2 * B), 256, 0, stream>>>(
        qb, kb, vTb, aobf, 0, 1);
    GP eo = mkOP(0, WA + (size_t)(0 * 4 + 3) * WSTEP, enc_attn_b + 3 * DIM,
                 xsrc, xbf_src, enc_norm_g, enc_norm_b, nullptr);
    GP dd = mkOP(1, WA + (size_t)(2 * 4 + 3) * WSTEP, dec_sa_b + 3 * DIM,
                 xtgt, xbf_tgt, dec_norm_g, dec_norm_b, nullptr);
    op2(eo, dd);
  }
  ffpair(xbf_src, 0, enc_ff_b1, enc_ff_mod, enc_ff_b2, xsrc, xbf_src,
         enc_norm_g + 1 * DIM, enc_norm_b + 1 * DIM, nullptr);
  // ---- enc.l1
  {
    GP e = mkQKV(xbf_src, WA + (size_t)(1 * 4) * WSTEP,
                 enc_attn_b + (size_t)1 * 4 * DIM, 0);
    qkv1(e);
    attn1(0);
    GP eo = mkOP(0, WA + (size_t)(1 * 4 + 3) * WSTEP,
                 enc_attn_b + (size_t)1 * 4 * DIM + 3 * DIM,
                 xsrc, xbf_src, enc_norm_g + 2 * DIM, enc_norm_b + 2 * DIM, nullptr);
    op1(eo);
  }
  ffpair(xbf_src, 1, enc_ff_b1 + (size_t)1 * H * 4, enc_ff_mod + H,
         enc_ff_b2 + DIM, xsrc, xbf_src,
         enc_norm_g + 3 * DIM, enc_norm_b + 3 * DIM, nullptr);

  // ---- decoder layers
  for (int l = 0; l < LD; ++l) {
    if (l > 0) {
      GP d = mkQKV(xbf_tgt, WA + (size_t)((2 + l) * 4) * WSTEP,
                   dec_sa_b + (size_t)l * 4 * DIM, 0);
      qkv1(d);
      attn1(1);
      GP od = mkOP(0, WA + (size_t)((2 + l) * 4 + 3) * WSTEP,
                   dec_sa_b + (size_t)l * 4 * DIM + 3 * DIM,
                   xtgt, xbf_tgt, dec_norm_g + (size_t)(l * 3) * DIM,
                   dec_norm_b + (size_t)(l * 3) * DIM, nullptr);
      op1(od);
    }
    {
      GP g = mkQKV(xbf_tgt, WA + (size_t)((4 + l) * 4) * WSTEP,
                   dec_ca_b + (size_t)l * 4 * DIM, 0);
      g.Aalt = xbf_src; g.altStart = DIM;
      qkv1(g);
      attn1(0);
      GP og = mkOP(0, WA + (size_t)((4 + l) * 4 + 3) * WSTEP,
                   dec_ca_b + (size_t)l * 4 * DIM + 3 * DIM,
                   xtgt, xbf_tgt, dec_norm_g + (size_t)(l * 3 + 1) * DIM,
                   dec_norm_b + (size_t)(l * 3 + 1) * DIM, nullptr);
      op1(og);
    }
    ffpair(xbf_tgt, 2 + l, dec_ff_b1 + (size_t)l * H * 4,
           dec_ff_mod + (size_t)l * H, dec_ff_b2 + (size_t)l * DIM,
           xtgt, xbf_tgt, dec_norm_g + (size_t)(l * 3 + 2) * DIM,
           dec_norm_b + (size_t)(l * 3 + 2) * DIM,
           (l == LD - 1) ? realbf : nullptr);
  }

  // logits
  {
    GP g = Z;
    g.A = realbf; g.Bt = Wfc; g.bias = fc_b; g.Cv = out;
    gemm2w_kernel<0><<<(V / 128) * (BT / 128), 128, 0, stream>>>(
        g, g, 1, V, 256);
  }
}

// Round 11
// 1091.751 us; speedup vs baseline: 1.3614x; 1.3614x over previous
//
#include <hip/hip_runtime.h>
#include <math.h>

#define B 4
#define T 512
#define D 256
#define H 1024
#define NH 8
#define V 32000
#define BT (B*T)
#define LE 2
#define LD 2
#define DIM 1024  // expanded width = 4*D

typedef __attribute__((ext_vector_type(8))) short s16x8;
typedef __attribute__((ext_vector_type(4))) float f32x4;
typedef __attribute__((address_space(3))) void lds_void;
typedef const __attribute__((address_space(1))) void g_void;

__device__ __forceinline__ ushort f2bf(float x) {
  uint u = __float_as_uint(x);
  return (ushort)((u + 0x7fffu + ((u >> 16) & 1u)) >> 16);
}

#define QSCALE 0.08838834764831845f  // 1/sqrt(128), baked into Q at QKV epilogue

// ---------------------------------------------------------------------------
// ONE launch: all weight expansion + fc convert + BOTH embeds
#define A_CNT  1572864
#define F_CNT  2097152
#define FC_CNT 2048000
#define EMB_CNT (2 * BT * 256)
#define MEGA_TOT (A_CNT + F_CNT + FC_CNT + EMB_CNT)
#define WSTEP  1048576   // DIM*DIM elems
#define FFW    4194304   // 4H*DIM elems

__device__ __forceinline__ void qexpand_write(
    const float* __restrict__ src, ushort* __restrict__ dst,
    int o, int d, int Din, int P) {
  float w0 = src[(size_t)o * Din + d];
  float w1 = src[P + (size_t)o * Din + d];
  float w2 = src[2 * (size_t)P + (size_t)o * Din + d];
  float w3 = src[3 * (size_t)P + (size_t)o * Din + d];
  int K4 = Din * 4;
  size_t rbase = (size_t)(o * 4) * K4 + d * 4;
  *(ushort4*)(dst + rbase)          = make_ushort4(f2bf(w0), f2bf(-w1), f2bf(-w2), f2bf(-w3));
  *(ushort4*)(dst + rbase + K4)     = make_ushort4(f2bf(w1), f2bf(w0),  f2bf(w3),  f2bf(-w2));
  *(ushort4*)(dst + rbase + 2 * K4) = make_ushort4(f2bf(w2), f2bf(-w3), f2bf(w0),  f2bf(w1));
  *(ushort4*)(dst + rbase + 3 * K4) = make_ushort4(f2bf(w3), f2bf(w2),  f2bf(-w1), f2bf(w0));
}

__global__ __launch_bounds__(256) void mega_expand_kernel(
    const float* __restrict__ encA, const float* __restrict__ decSA,
    const float* __restrict__ decCA,
    const float* __restrict__ eW1, const float* __restrict__ eW2,
    const float* __restrict__ dW1, const float* __restrict__ dW2,
    const float* __restrict__ fcW,
    ushort* __restrict__ WA, ushort* __restrict__ WF, ushort* __restrict__ Wfc,
    const int* __restrict__ srcIds, const int* __restrict__ tgtIds,
    const float* __restrict__ emb,
    float* __restrict__ xsrc, ushort* __restrict__ xbfs,
    float* __restrict__ xtgt, ushort* __restrict__ xbft) {
  int gid = blockIdx.x * 256 + threadIdx.x;
  if (gid < A_CNT) {
    int u = gid >> 18;
    int p = (gid >> 16) & 3;
    int rem = gid & 65535;
    int o = rem >> 8, d = rem & 255;
    const float* base = (u < 2) ? encA + (size_t)u * 1048576
                      : (u < 4) ? decSA + (size_t)(u - 2) * 1048576
                                : decCA + (size_t)(u - 4) * 1048576;
    qexpand_write(base + (size_t)p * 262144,
                  WA + ((size_t)u * 4 + p) * WSTEP, o, d, 256, 65536);
  } else if (gid < A_CNT + F_CNT) {
    int idx = gid - A_CNT;
    int layer = idx >> 19;
    int w12 = (idx >> 18) & 1;
    int rem = idx & 262143;
    const float* w1b = (layer < 2) ? eW1 + (size_t)layer * 1048576
                                   : dW1 + (size_t)(layer - 2) * 1048576;
    const float* w2b = (layer < 2) ? eW2 + (size_t)layer * 1048576
                                   : dW2 + (size_t)(layer - 2) * 1048576;
    ushort* dst = WF + (size_t)layer * 2 * FFW + (size_t)w12 * FFW;
    if (w12 == 0) {
      int o = rem >> 8, d = rem & 255;
      qexpand_write(w1b, dst, o, d, 256, 262144);
    } else {
      int o = rem >> 10, d = rem & 1023;
      qexpand_write(w2b, dst, o, d, 1024, 262144);
    }
  } else if (gid < A_CNT + F_CNT + FC_CNT) {
    int idx = gid - A_CNT - F_CNT;
    float4 v = ((const float4*)fcW)[idx];
    ((ushort4*)Wfc)[idx] = make_ushort4(f2bf(v.x), f2bf(v.y), f2bf(v.z), f2bf(v.w));
  } else if (gid < MEGA_TOT) {
    int idx = gid - A_CNT - F_CNT - FC_CNT;
    int g = idx >> 8, d = idx & 255;
    int isTgt = g >= BT;
    int bt = isTgt ? g - BT : g;
    int id = isTgt ? tgtIds[bt] : srcIds[bt];
    float* out = isTgt ? xtgt : xsrc;
    ushort* outbf = isTgt ? xbft : xbfs;
    int t = bt % T;
    size_t VD = (size_t)V * D;
    float scale = powf(10000.f, -(float)d / (float)D);
    float r = emb[(size_t)id * D + d];
    float i = emb[VD + (size_t)id * D + d] * scale;
    float j = emb[2 * VD + (size_t)id * D + d] * scale;
    float k = emb[3 * VD + (size_t)id * D + d] * scale;
    float n = sqrtf(r * r + i * i + j * j + k * k + 1e-6f);
    float ang;
    if (d < D / 2) {
      float inv = powf(10000.f, -(float)(2 * d) / (float)D);
      ang = sinf((float)t * inv);
    } else {
      float inv = powf(10000.f, -(float)(2 * (d - D / 2)) / (float)D);
      ang = cosf((float)t * inv);
    }
    float s = ang / n;
    size_t base = (size_t)bt * DIM + d * 4;
    float4 q = make_float4(r * s, i * s, j * s, k * s);
    *(float4*)(out + base) = q;
    *(ushort4*)(outbf + base) = make_ushort4(f2bf(q.x), f2bf(q.y), f2bf(q.z), f2bf(q.w));
  }
}

// ---------------------------------------------------------------------------
// Unit-routed GEMM params
struct GP {
  const ushort* A; const ushort* Aalt; int altStart;
  const ushort* Bt; const float* bias; void* Cv;
  ushort* qo; ushort* ko; ushort* vo;
  float* xres; ushort* xbf; const float* gg; const float* bb;
  const float* modb; ushort* realout;
};

// ---------------------------------------------------------------------------
// 4-wave GEMM (r9-proven core). TM=128: 2-buffer, 1 barrier/K-step.
// TM=64 (grid-capped OP/FF2 dispatches): 4-buffer, 2 K-steps per barrier —
// halves barrier-drain events where blocks/CU==1 and TLP can't hide latency.
// OMODE 0: f32+bias. OMODE 3: QKV epilogue (Q pre-scaled). OMODE 4:
// +resid+qnorm(+real). OMODE 5: +modrelu -> bf16.
template <int OMODE, int TM>
__global__ __launch_bounds__(256, 4) void gemm_bf16_kernel(
    GP u0, GP u1, int nunits, int N, int K) {
  constexpr int NBUF = (TM == 64) ? 4 : 2;
  __shared__ ushort As[NBUF][TM * 32];
  __shared__ ushort Bs[NBUF][128 * 32];
  const int tid = threadIdx.x;
  const int w = tid >> 6, l = tid & 63;
  const int nwg = gridDim.x;
  const int qq = nwg >> 3, rr = nwg & 7;
  const int xcd = blockIdx.x & 7, pos = blockIdx.x >> 3;
  const int wg = (xcd < rr ? xcd * (qq + 1) : rr * (qq + 1) + (xcd - rr) * qq) + pos;
  const int uwg = nwg / nunits;
  const int unit = wg / uwg;
  const int wgl = wg - unit * uwg;
  GP U = unit ? u1 : u0;
  const int nbx = N >> 7;
  const int nby = uwg / nbx;
  const int m0 = (wgl % nby) * TM, n0 = (wgl / nby) * 128;
  const ushort* Ap = (U.altStart && n0 >= U.altStart) ? U.Aalt : U.A;
  const ushort* Btp = U.Bt;
  const int lr = l & 15, lg = l >> 4;
  constexpr int NR = (TM == 128) ? 4 : 2;
  const int wm = (TM == 128) ? (w >> 1) : 0;
  const int wn = (TM == 128) ? (w & 1) : w;
  const int wcol = wn * (NR * 16);
  f32x4 acc[4][NR] = {};
  const int NT = K >> 5;

  auto stage = [&](int t, int buf) {
    int k0 = t << 5;
#pragma unroll
    for (int s = 0; s < TM / 64; ++s) {
      int fb = (w * (TM / 64) + s) * 1024;
      int f = fb + l * 16;
      int row = f >> 6, cb = (f & 63) >> 1;
      __builtin_amdgcn_global_load_lds(
          (g_void*)(Ap + (size_t)(m0 + row) * K + k0 + cb),
          (lds_void*)((char*)&As[buf][0] + fb), 16, 0, 0);
    }
#pragma unroll
    for (int s = 0; s < 2; ++s) {
      int fb = (w * 2 + s) * 1024;
      int f = fb + l * 16;
      int row = f >> 6, cb = (f & 63) >> 1;
      __builtin_amdgcn_global_load_lds(
          (g_void*)(Btp + (size_t)(n0 + row) * K + k0 + cb),
          (lds_void*)((char*)&Bs[buf][0] + fb), 16, 0, 0);
    }
  };
  auto compute = [&](int buf) {
    s16x8 af[4], bfr[NR];
#pragma unroll
    for (int mi = 0; mi < 4; ++mi)
      af[mi] = *(const s16x8*)(&As[buf][0] + (wm * 64 + mi * 16 + lr) * 32 + lg * 8);
#pragma unroll
    for (int ni = 0; ni < NR; ++ni)
      bfr[ni] = *(const s16x8*)(&Bs[buf][0] + (wcol + ni * 16 + lr) * 32 + lg * 8);
    __builtin_amdgcn_s_setprio(1);
#pragma unroll
    for (int mi = 0; mi < 4; ++mi)
#pragma unroll
      for (int ni = 0; ni < NR; ++ni)
        acc[mi][ni] = __builtin_amdgcn_mfma_f32_16x16x32_bf16(af[mi], bfr[ni], acc[mi][ni], 0, 0, 0);
    __builtin_amdgcn_s_setprio(0);
  };

  if constexpr (TM == 64) {
    // 4-buffer, 2 K-steps per barrier (NT is even: K = 1024 or 4096)
    stage(0, 0);
    stage(1, 1);
    __syncthreads();
    for (int t = 0; t < NT; t += 2) {
      if (t + 2 < NT) {
        stage(t + 2, (t + 2) & 3);
        stage(t + 3, (t + 3) & 3);
      }
      compute(t & 3);
      compute((t + 1) & 3);
      __syncthreads();
    }
  } else {
    stage(0, 0);
    __syncthreads();
    int cur = 0;
    for (int t = 0; t < NT; ++t) {
      if (t + 1 < NT) stage(t + 1, cur ^ 1);
      compute(cur);
      __syncthreads();
      cur ^= 1;
    }
  }

#pragma unroll
  for (int mi = 0; mi < 4; ++mi) {
#pragma unroll
    for (int ni = 0; ni < NR; ++ni) {
      int row = m0 + wm * 64 + mi * 16 + lg * 4;
      int col = n0 + wcol + ni * 16 + lr;
      f32x4 v = acc[mi][ni];
      if constexpr (OMODE == 0) {
        float bv = U.bias ? U.bias[col] : 0.f;
        float* C = (float*)U.Cv;
#pragma unroll
        for (int r = 0; r < 4; ++r)
          C[(size_t)(row + r) * N + col] = v[r] + bv;
      } else if constexpr (OMODE == 3) {
        float bv = U.bias[col];
        if (col < 2048) {
          ushort* dst = (col < DIM) ? U.qo : U.ko;
          float sc = (col < DIM) ? QSCALE : 1.f;
          int c = col & (DIM - 1);
#pragma unroll
          for (int r = 0; r < 4; ++r)
            dst[(size_t)(row + r) * DIM + c] = f2bf((v[r] + bv) * sc);
        } else {
          int c = col - 2048;
          ushort4 o4 = make_ushort4(f2bf(v[0] + bv), f2bf(v[1] + bv),
                                    f2bf(v[2] + bv), f2bf(v[3] + bv));
          *(ushort4*)&U.vo[((size_t)((row >> 9) << 10) + c) * T + (row & 511)] = o4;
        }
      } else if constexpr (OMODE == 4) {
        float bv = U.bias[col];
        float gv = U.gg[col], bev = U.bb[col];
#pragma unroll
        for (int r = 0; r < 4; ++r) {
          float val = v[r] + bv + U.xres[(size_t)(row + r) * DIM + col];
          float sq = val * val;
          sq += __shfl_xor(sq, 1);
          sq += __shfl_xor(sq, 2);
          float invn = rsqrtf(sq + 1e-6f);
          float res = gv * (val * invn) + bev;
          U.xres[(size_t)(row + r) * DIM + col] = res;
          U.xbf[(size_t)(row + r) * DIM + col] = f2bf(res);
          if (U.realout) {
            float rsq = res * res;
            rsq += __shfl_xor(rsq, 1);
            rsq += __shfl_xor(rsq, 2);
            if ((col & 3) == 0)
              U.realout[(size_t)(row + r) * D + (col >> 2)] = f2bf(sqrtf(rsq));
          }
        }
      } else {  // OMODE 5: modrelu
        float bv = U.bias[col];
        float mb = U.modb[col >> 2];
        ushort* C = (ushort*)U.Cv;
#pragma unroll
        for (int r = 0; r < 4; ++r) {
          float val = v[r] + bv;
          float sq = val * val;
          sq += __shfl_xor(sq, 1);
          sq += __shfl_xor(sq, 2);
          float norm = sqrtf(sq);
          float scale = fmaxf(norm + mb, 0.f) / (norm + 1e-6f);
          C[(size_t)(row + r) * N + col] = f2bf(val * scale);
        }
      }
    }
  }
}

// ---------------------------------------------------------------------------
// fused flash attention, head-dim 128. grid (T/64, NH, B*npair), 4 waves.
// Q pre-scaled in QKV epilogue. Defer-max (THR=8) skips O-rescale.
__global__ __launch_bounds__(256) void fused_attn_kernel(
    const ushort* __restrict__ qb, const ushort* __restrict__ kb,
    const ushort* __restrict__ vT, ushort* __restrict__ outA,
    int c0, int c1) {
  __shared__ ushort Ks[2][64 * 128];
  __shared__ ushort Vs[2][128 * 64];
  __shared__ ushort Pst[4][1024];
  const int tid = threadIdx.x;
  const int wq = tid >> 6, l = tid & 63;
  const int lr = l & 15, lg = l >> 4;
  const int h = blockIdx.y;
  const int u = blockIdx.z >> 2, b = blockIdx.z & 3;
  const size_t uoff = (size_t)u * ((size_t)BT * DIM);
  const int causal = u ? c1 : c0;
  const int q0 = blockIdx.x * 64 + wq * 16;
  const size_t bT = (size_t)b * T;
  const int hc = h * 128;
  const size_t vrow0 = (size_t)(b * NH + h) * 128;
  const ushort* qbu = qb + uoff;
  const ushort* kbu = kb + uoff;
  const ushort* vTu = vT + uoff;
  ushort* outu = outA + uoff;
  s16x8 qf[4];
#pragma unroll
  for (int ks = 0; ks < 4; ++ks)
    qf[ks] = *(const s16x8*)(qbu + (bT + q0 + lr) * DIM + hc + ks * 32 + lg * 8);
  f32x4 O[8] = {};
  float m[4] = {-3e38f, -3e38f, -3e38f, -3e38f};
  float lac[4] = {0.f, 0.f, 0.f, 0.f};
  const int kend = causal ? (blockIdx.x + 1) * 64 : T;
  const int ntile = kend >> 6;

  auto stageKV = [&](int tile, int buf) {
    int kv0 = tile << 6;
#pragma unroll
    for (int s = 0; s < 4; ++s) {
      int f = s * 4096 + tid * 16;
      int row = f >> 8, g = (f >> 4) & 15;
      int gs = g ^ (row & 7);
      __builtin_amdgcn_global_load_lds(
          (g_void*)(kbu + (bT + kv0 + row) * DIM + hc + gs * 8),
          (lds_void*)((char*)&Ks[buf][0] + f), 16, 0, 0);
    }
#pragma unroll
    for (int s = 0; s < 4; ++s) {
      int f = s * 4096 + tid * 16;
      int row = f >> 7, g = (f >> 4) & 7;
      int gs = g ^ (row & 7);
      __builtin_amdgcn_global_load_lds(
          (g_void*)(vTu + (vrow0 + row) * T + kv0 + gs * 8),
          (lds_void*)((char*)&Vs[buf][0] + f), 16, 0, 0);
    }
  };

  stageKV(0, 0);
  __syncthreads();
  int cur = 0;
  for (int tile = 0; tile < ntile; ++tile) {
    const int kv0 = tile << 6;
    if (tile + 1 < ntile) stageKV(tile + 1, cur ^ 1);
    f32x4 s[4] = {};
#pragma unroll
    for (int ks = 0; ks < 4; ++ks) {
      s16x8 kf[4];
#pragma unroll
      for (int ni = 0; ni < 4; ++ni) {
        int row = ni * 16 + lr;
        int g = (ks * 4 + lg) ^ (row & 7);
        kf[ni] = *(const s16x8*)(&Ks[cur][0] + row * 128 + g * 8);
      }
#pragma unroll
      for (int ni = 0; ni < 4; ++ni)
        s[ni] = __builtin_amdgcn_mfma_f32_16x16x32_bf16(qf[ks], kf[ni], s[ni], 0, 0, 0);
    }
    const bool domask = causal && (kv0 + 63 > q0);
#pragma unroll
    for (int r = 0; r < 4; ++r) {
      const int qrow = q0 + lg * 4 + r;
      float mx = -3e38f;
#pragma unroll
      for (int ni = 0; ni < 4; ++ni) {
        float v = s[ni][r];
        if (domask && (kv0 + ni * 16 + lr > qrow)) v = -3e38f;
        s[ni][r] = v;
        mx = fmaxf(mx, v);
      }
#pragma unroll
      for (int dd = 1; dd < 16; dd <<= 1) mx = fmaxf(mx, __shfl_xor(mx, dd));
      if (__ballot(mx > m[r] + 8.f)) {
        float mn = fmaxf(m[r], mx);
        float alpha = __expf(m[r] - mn);
        m[r] = mn;
        lac[r] *= alpha;
#pragma unroll
        for (int dni = 0; dni < 8; ++dni) O[dni][r] *= alpha;
      }
      float ps = 0.f;
#pragma unroll
      for (int ni = 0; ni < 4; ++ni) {
        float p = __expf(s[ni][r] - m[r]);
        s[ni][r] = p;
        ps += p;
      }
#pragma unroll
      for (int dd = 1; dd < 16; dd <<= 1) ps += __shfl_xor(ps, dd);
      lac[r] += ps;
      const int qloc = lg * 4 + r;
      const int sw = (qloc & 7) << 3;
#pragma unroll
      for (int ni = 0; ni < 4; ++ni)
        Pst[wq][qloc * 64 + ((ni * 16 + lr) ^ sw)] = f2bf(s[ni][r]);
    }
    asm volatile("s_waitcnt lgkmcnt(0)" ::: "memory");
    __builtin_amdgcn_sched_barrier(0);
#pragma unroll
    for (int ks2 = 0; ks2 < 2; ++ks2) {
      s16x8 pa = *(const s16x8*)&Pst[wq][lr * 64 + ((ks2 * 32 + lg * 8) ^ ((lr & 7) << 3))];
#pragma unroll
      for (int dni = 0; dni < 8; ++dni) {
        int row = dni * 16 + lr;
        int g = (ks2 * 4 + lg) ^ (row & 7);
        s16x8 vf = *(const s16x8*)(&Vs[cur][0] + row * 64 + g * 8);
        O[dni] = __builtin_amdgcn_mfma_f32_16x16x32_bf16(pa, vf, O[dni], 0, 0, 0);
      }
    }
    __syncthreads();
    cur ^= 1;
  }
#pragma unroll
  for (int r = 0; r < 4; ++r) {
    float inv = 1.f / lac[r];
    const size_t row = bT + q0 + lg * 4 + r;
#pragma unroll
    for (int dni = 0; dni < 8; ++dni)
      outu[row * DIM + hc + dni * 16 + lr] = f2bf(O[dni][r] * inv);
  }
}

// ---------------------------------------------------------------------------
extern "C" void kernel_launch(void* const* d_in, const int* in_sizes, int n_in,
                              void* d_out, int out_size, void* d_ws, size_t ws_size,
                              hipStream_t stream) {
  const int*   src        = (const int*)d_in[0];
  const int*   tgt        = (const int*)d_in[1];
  const float* emb        = (const float*)d_in[3];
  const float* enc_attn_W = (const float*)d_in[4];
  const float* enc_attn_b = (const float*)d_in[5];
  const float* enc_norm_g = (const float*)d_in[6];
  const float* enc_norm_b = (const float*)d_in[7];
  const float* enc_ff_W1  = (const float*)d_in[8];
  const float* enc_ff_b1  = (const float*)d_in[9];
  const float* enc_ff_mod = (const float*)d_in[10];
  const float* enc_ff_W2  = (const float*)d_in[11];
  const float* enc_ff_b2  = (const float*)d_in[12];
  const float* dec_sa_W   = (const float*)d_in[13];
  const float* dec_sa_b   = (const float*)d_in[14];
  const float* dec_ca_W   = (const float*)d_in[15];
  const float* dec_ca_b   = (const float*)d_in[16];
  const float* dec_norm_g = (const float*)d_in[17];
  const float* dec_norm_b = (const float*)d_in[18];
  const float* dec_ff_W1  = (const float*)d_in[19];
  const float* dec_ff_b1  = (const float*)d_in[20];
  const float* dec_ff_mod = (const float*)d_in[21];
  const float* dec_ff_W2  = (const float*)d_in[22];
  const float* dec_ff_b2  = (const float*)d_in[23];
  const float* fc_W       = (const float*)d_in[24];
  const float* fc_b       = (const float*)d_in[25];
  float* out = (float*)d_out;

  const size_t USZ = (size_t)BT * DIM;
  float* ws    = (float*)d_ws;
  float* xsrc  = ws;
  float* xtgt  = xsrc + USZ;
  ushort* xbf_src = (ushort*)(xtgt + USZ);
  ushort* xbf_tgt = xbf_src + USZ;
  ushort* aobf    = xbf_tgt + USZ;      // 2 units
  ushort* qb      = aobf + 2 * USZ;     // 2 units
  ushort* kb      = qb + 2 * USZ;       // 2 units
  ushort* vTb     = kb + 2 * USZ;       // 2 units
  ushort* hbf     = vTb + 2 * USZ;      // BT*4096
  ushort* realbf  = hbf + (size_t)BT * H * 4;
  ushort* WA      = realbf + (size_t)BT * D;      // 24 * WSTEP
  ushort* WF      = WA + (size_t)6 * 4 * WSTEP;   // 8 * FFW
  ushort* Wfc     = WF + (size_t)4 * 2 * FFW;     // V*D

  mega_expand_kernel<<<(MEGA_TOT + 255) / 256, 256, 0, stream>>>(
      enc_attn_W, dec_sa_W, dec_ca_W,
      enc_ff_W1, enc_ff_W2, dec_ff_W1, dec_ff_W2, fc_W, WA, WF, Wfc,
      src, tgt, emb, xsrc, xbf_src, xtgt, xbf_tgt);

  GP Z{};

  auto mkQKV = [&](const ushort* Abf, const ushort* Wu, const float* bb, int u) {
    GP g = Z;
    g.A = Abf; g.Bt = Wu; g.bias = bb;
    g.qo = qb + u * USZ; g.ko = kb + u * USZ; g.vo = vTb + u * USZ;
    return g;
  };
  auto mkOP = [&](int u, const ushort* Wu3, const float* bb, float* xres,
                  ushort* xbf, const float* gg, const float* nb, ushort* realo) {
    GP g = Z;
    g.A = aobf + u * USZ; g.Bt = Wu3; g.bias = bb;
    g.xres = xres; g.xbf = xbf; g.gg = gg; g.bb = nb; g.realout = realo;
    return g;
  };

  auto qkv1 = [&](GP g) {
    gemm_bf16_kernel<3, 128><<<384, 256, 0, stream>>>(g, g, 1, 3 * DIM, DIM);
  };
  auto qkv2 = [&](GP g0, GP g1) {
    gemm_bf16_kernel<3, 128><<<768, 256, 0, stream>>>(g0, g1, 2, 3 * DIM, DIM);
  };
  auto op1 = [&](GP g) {
    gemm_bf16_kernel<4, 64><<<256, 256, 0, stream>>>(g, g, 1, DIM, DIM);
  };
  auto op2 = [&](GP g0, GP g1) {
    gemm_bf16_kernel<4, 64><<<512, 256, 0, stream>>>(g0, g1, 2, DIM, DIM);
  };
  auto attn1 = [&](int causal) {
    fused_attn_kernel<<<dim3(T / 64, NH, B), 256, 0, stream>>>(
        qb, kb, vTb, aobf, causal, causal);
  };
  auto ffpair = [&](const ushort* xbf, int layer, const float* b1,
                    const float* mod, const float* b2, float* xres,
                    ushort* xbfo, const float* gg, const float* nb,
                    ushort* realo) {
    const ushort* Wf = WF + (size_t)layer * 2 * FFW;
    GP g1 = Z;
    g1.A = xbf; g1.Bt = Wf; g1.bias = b1; g1.Cv = hbf; g1.modb = mod;
    gemm_bf16_kernel<5, 128><<<512, 256, 0, stream>>>(g1, g1, 1, 4 * H, DIM);
    GP g2 = Z;
    g2.A = hbf; g2.Bt = Wf + FFW; g2.bias = b2;
    g2.xres = xres; g2.xbf = xbfo; g2.gg = gg; g2.bb = nb; g2.realout = realo;
    gemm_bf16_kernel<4, 64><<<256, 256, 0, stream>>>(g2, g2, 1, DIM, 4 * H);
  };

  // ---- enc.l0 ∥ dec.sa0 : merged QKV / attn / out-proj
  {
    GP e = mkQKV(xbf_src, WA + (size_t)(0 * 4) * WSTEP, enc_attn_b, 0);
    GP d = mkQKV(xbf_tgt, WA + (size_t)(2 * 4) * WSTEP, dec_sa_b, 1);
    qkv2(e, d);
    fused_attn_kernel<<<dim3(T / 64, NH, 2 * B), 256, 0, stream>>>(
        qb, kb, vTb, aobf, 0, 1);
    GP eo = mkOP(0, WA + (size_t)(0 * 4 + 3) * WSTEP, enc_attn_b + 3 * DIM,
                 xsrc, xbf_src, enc_norm_g, enc_norm_b, nullptr);
    GP dd = mkOP(1, WA + (size_t)(2 * 4 + 3) * WSTEP, dec_sa_b + 3 * DIM,
                 xtgt, xbf_tgt, dec_norm_g, dec_norm_b, nullptr);
    op2(eo, dd);
  }
  ffpair(xbf_src, 0, enc_ff_b1, enc_ff_mod, enc_ff_b2, xsrc, xbf_src,
         enc_norm_g + 1 * DIM, enc_norm_b + 1 * DIM, nullptr);
  // ---- enc.l1
  {
    GP e = mkQKV(xbf_src, WA + (size_t)(1 * 4) * WSTEP,
                 enc_attn_b + (size_t)1 * 4 * DIM, 0);
    qkv1(e);
    attn1(0);
    GP eo = mkOP(0, WA + (size_t)(1 * 4 + 3) * WSTEP,
                 enc_attn_b + (size_t)1 * 4 * DIM + 3 * DIM,
                 xsrc, xbf_src, enc_norm_g + 2 * DIM, enc_norm_b + 2 * DIM, nullptr);
    op1(eo);
  }
  ffpair(xbf_src, 1, enc_ff_b1 + (size_t)1 * H * 4, enc_ff_mod + H,
         enc_ff_b2 + DIM, xsrc, xbf_src,
         enc_norm_g + 3 * DIM, enc_norm_b + 3 * DIM, nullptr);

  // ---- decoder layers
  for (int l = 0; l < LD; ++l) {
    if (l > 0) {
      GP d = mkQKV(xbf_tgt, WA + (size_t)((2 + l) * 4) * WSTEP,
                   dec_sa_b + (size_t)l * 4 * DIM, 0);
      qkv1(d);
      attn1(1);
      GP od = mkOP(0, WA + (size_t)((2 + l) * 4 + 3) * WSTEP,
                   dec_sa_b + (size_t)l * 4 * DIM + 3 * DIM,
                   xtgt, xbf_tgt, dec_norm_g + (size_t)(l * 3) * DIM,
                   dec_norm_b + (size_t)(l * 3) * DIM, nullptr);
      op1(od);
    }
    {
      GP g = mkQKV(xbf_tgt, WA + (size_t)((4 + l) * 4) * WSTEP,
                   dec_ca_b + (size_t)l * 4 * DIM, 0);
      g.Aalt = xbf_src; g.altStart = DIM;
      qkv1(g);
      attn1(0);
      GP og = mkOP(0, WA + (size_t)((4 + l) * 4 + 3) * WSTEP,
                   dec_ca_b + (size_t)l * 4 * DIM + 3 * DIM,
                   xtgt, xbf_tgt, dec_norm_g + (size_t)(l * 3 + 1) * DIM,
                   dec_norm_b + (size_t)(l * 3 + 1) * DIM, nullptr);
      op1(og);
    }
    ffpair(xbf_tgt, 2 + l, dec_ff_b1 + (size_t)l * H * 4,
           dec_ff_mod + (size_t)l * H, dec_ff_b2 + (size_t)l * DIM,
           xtgt, xbf_tgt, dec_norm_g + (size_t)(l * 3 + 2) * DIM,
           dec_norm_b + (size_t)(l * 3 + 2) * DIM,
           (l == LD - 1) ? realbf : nullptr);
  }

  // logits
  {
    GP g = Z;
    g.A = realbf; g.Bt = Wfc; g.bias = fc_b; g.Cv = out;
    gemm_bf16_kernel<0, 128><<<(V / 128) * (BT / 128), 256, 0, stream>>>(
        g, g, 1, V, 256);
  }
}

// Round 12
// 961.672 us; speedup vs baseline: 1.5455x; 1.1353x over previous
//
#include <hip/hip_runtime.h>
#include <math.h>

#define B 4
#define T 512
#define D 256
#define H 1024
#define NH 8
#define V 32000
#define BT (B*T)
#define LE 2
#define LD 2
#define DIM 1024  // expanded width = 4*D

typedef __attribute__((ext_vector_type(8))) short s16x8;
typedef __attribute__((ext_vector_type(4))) float f32x4;
typedef __attribute__((address_space(3))) void lds_void;
typedef const __attribute__((address_space(1))) void g_void;

__device__ __forceinline__ ushort f2bf(float x) {
  uint u = __float_as_uint(x);
  return (ushort)((u + 0x7fffu + ((u >> 16) & 1u)) >> 16);
}
__device__ __forceinline__ float bf2f(ushort u) {
  return __uint_as_float(((uint)u) << 16);
}

#define QSCALE 0.08838834764831845f  // 1/sqrt(128), baked into Q at QKV epilogue

// ---------------------------------------------------------------------------
// ONE launch: all weight expansion + fc convert + BOTH embeds
#define A_CNT  1572864
#define F_CNT  2097152
#define FC_CNT 2048000
#define EMB_CNT (2 * BT * 256)
#define MEGA_TOT (A_CNT + F_CNT + FC_CNT + EMB_CNT)
#define WSTEP  1048576   // DIM*DIM elems
#define FFW    4194304   // 4H*DIM elems

__device__ __forceinline__ void qexpand_write(
    const float* __restrict__ src, ushort* __restrict__ dst,
    int o, int d, int Din, int P) {
  float w0 = src[(size_t)o * Din + d];
  float w1 = src[P + (size_t)o * Din + d];
  float w2 = src[2 * (size_t)P + (size_t)o * Din + d];
  float w3 = src[3 * (size_t)P + (size_t)o * Din + d];
  int K4 = Din * 4;
  size_t rbase = (size_t)(o * 4) * K4 + d * 4;
  *(ushort4*)(dst + rbase)          = make_ushort4(f2bf(w0), f2bf(-w1), f2bf(-w2), f2bf(-w3));
  *(ushort4*)(dst + rbase + K4)     = make_ushort4(f2bf(w1), f2bf(w0),  f2bf(w3),  f2bf(-w2));
  *(ushort4*)(dst + rbase + 2 * K4) = make_ushort4(f2bf(w2), f2bf(-w3), f2bf(w0),  f2bf(w1));
  *(ushort4*)(dst + rbase + 3 * K4) = make_ushort4(f2bf(w3), f2bf(w2),  f2bf(-w1), f2bf(w0));
}

__global__ __launch_bounds__(256) void mega_expand_kernel(
    const float* __restrict__ encA, const float* __restrict__ decSA,
    const float* __restrict__ decCA,
    const float* __restrict__ eW1, const float* __restrict__ eW2,
    const float* __restrict__ dW1, const float* __restrict__ dW2,
    const float* __restrict__ fcW,
    ushort* __restrict__ WA, ushort* __restrict__ WF, ushort* __restrict__ Wfc,
    const int* __restrict__ srcIds, const int* __restrict__ tgtIds,
    const float* __restrict__ emb,
    float* __restrict__ xsrc, ushort* __restrict__ xbfs,
    float* __restrict__ xtgt, ushort* __restrict__ xbft) {
  int gid = blockIdx.x * 256 + threadIdx.x;
  if (gid < A_CNT) {
    int u = gid >> 18;
    int p = (gid >> 16) & 3;
    int rem = gid & 65535;
    int o = rem >> 8, d = rem & 255;
    const float* base = (u < 2) ? encA + (size_t)u * 1048576
                      : (u < 4) ? decSA + (size_t)(u - 2) * 1048576
                                : decCA + (size_t)(u - 4) * 1048576;
    qexpand_write(base + (size_t)p * 262144,
                  WA + ((size_t)u * 4 + p) * WSTEP, o, d, 256, 65536);
  } else if (gid < A_CNT + F_CNT) {
    int idx = gid - A_CNT;
    int layer = idx >> 19;
    int w12 = (idx >> 18) & 1;
    int rem = idx & 262143;
    const float* w1b = (layer < 2) ? eW1 + (size_t)layer * 1048576
                                   : dW1 + (size_t)(layer - 2) * 1048576;
    const float* w2b = (layer < 2) ? eW2 + (size_t)layer * 1048576
                                   : dW2 + (size_t)(layer - 2) * 1048576;
    ushort* dst = WF + (size_t)layer * 2 * FFW + (size_t)w12 * FFW;
    if (w12 == 0) {
      int o = rem >> 8, d = rem & 255;
      qexpand_write(w1b, dst, o, d, 256, 262144);
    } else {
      int o = rem >> 10, d = rem & 1023;
      qexpand_write(w2b, dst, o, d, 1024, 262144);
    }
  } else if (gid < A_CNT + F_CNT + FC_CNT) {
    int idx = gid - A_CNT - F_CNT;
    float4 v = ((const float4*)fcW)[idx];
    ((ushort4*)Wfc)[idx] = make_ushort4(f2bf(v.x), f2bf(v.y), f2bf(v.z), f2bf(v.w));
  } else if (gid < MEGA_TOT) {
    int idx = gid - A_CNT - F_CNT - FC_CNT;
    int g = idx >> 8, d = idx & 255;
    int isTgt = g >= BT;
    int bt = isTgt ? g - BT : g;
    int id = isTgt ? tgtIds[bt] : srcIds[bt];
    float* out = isTgt ? xtgt : xsrc;
    ushort* outbf = isTgt ? xbft : xbfs;
    int t = bt % T;
    size_t VD = (size_t)V * D;
    float scale = powf(10000.f, -(float)d / (float)D);
    float r = emb[(size_t)id * D + d];
    float i = emb[VD + (size_t)id * D + d] * scale;
    float j = emb[2 * VD + (size_t)id * D + d] * scale;
    float k = emb[3 * VD + (size_t)id * D + d] * scale;
    float n = sqrtf(r * r + i * i + j * j + k * k + 1e-6f);
    float ang;
    if (d < D / 2) {
      float inv = powf(10000.f, -(float)(2 * d) / (float)D);
      ang = sinf((float)t * inv);
    } else {
      float inv = powf(10000.f, -(float)(2 * (d - D / 2)) / (float)D);
      ang = cosf((float)t * inv);
    }
    float s = ang / n;
    size_t base = (size_t)bt * DIM + d * 4;
    float4 q = make_float4(r * s, i * s, j * s, k * s);
    *(float4*)(out + base) = q;
    *(ushort4*)(outbf + base) = make_ushort4(f2bf(q.x), f2bf(q.y), f2bf(q.z), f2bf(q.w));
  }
}

// ---------------------------------------------------------------------------
// Unit-routed GEMM params
struct GP {
  const ushort* A; const ushort* Aalt; int altStart;
  const ushort* Bt; const float* bias; void* Cv;
  ushort* qo; ushort* ko; ushort* vo;
  float* xres; ushort* xbf; const float* gg; const float* bb;
  const float* modb; ushort* realout;
};

// ---------------------------------------------------------------------------
// 4-wave GEMM core. Routing: nunits independent GEMMs and/or nsplit K-slices
// per dispatch (split-K partials are deterministic: separate buffers).
// NBUF=2: 1 barrier/K-step. NBUF=4: 2 K-steps/barrier (grid-capped OP).
// OMODE 0: f32+bias. OMODE 3: QKV epilogue (Q pre-scaled). OMODE 4:
// +resid+qnorm(+real). OMODE 5: +modrelu->bf16. OMODE 6: bf16 K-partial.
template <int OMODE, int TM, int NBUF>
__global__ __launch_bounds__(256, 4) void gemm_bf16_kernel(
    GP u0, GP u1, int nunits, int nsplit, int N, int K) {
  __shared__ ushort As[NBUF][TM * 32];
  __shared__ ushort Bs[NBUF][128 * 32];
  const int tid = threadIdx.x;
  const int w = tid >> 6, l = tid & 63;
  const int nwg = gridDim.x;
  const int qq = nwg >> 3, rr = nwg & 7;
  const int xcd = blockIdx.x & 7, pos = blockIdx.x >> 3;
  const int wg = (xcd < rr ? xcd * (qq + 1) : rr * (qq + 1) + (xcd - rr) * qq) + pos;
  const int uwg = nwg / (nunits * nsplit);
  const int idx = wg / uwg;
  const int unit = idx / nsplit;
  const int split = idx % nsplit;
  const int wgl = wg % uwg;
  GP U = unit ? u1 : u0;
  const int Ksub = K / nsplit;
  const int kbase = split * Ksub;
  const int nbx = N >> 7;
  const int nby = uwg / nbx;
  const int m0 = (wgl % nby) * TM, n0 = (wgl / nby) * 128;
  const ushort* Ap = (U.altStart && n0 >= U.altStart) ? U.Aalt : U.A;
  const ushort* Btp = U.Bt;
  const int lr = l & 15, lg = l >> 4;
  constexpr int NR = (TM == 128) ? 4 : 2;
  const int wm = (TM == 128) ? (w >> 1) : 0;
  const int wn = (TM == 128) ? (w & 1) : w;
  const int wcol = wn * (NR * 16);
  f32x4 acc[4][NR] = {};
  const int NT = Ksub >> 5;

  auto stage = [&](int t, int buf) {
    int k0 = kbase + (t << 5);
#pragma unroll
    for (int s = 0; s < TM / 64; ++s) {
      int fb = (w * (TM / 64) + s) * 1024;
      int f = fb + l * 16;
      int row = f >> 6, cb = (f & 63) >> 1;
      __builtin_amdgcn_global_load_lds(
          (g_void*)(Ap + (size_t)(m0 + row) * K + k0 + cb),
          (lds_void*)((char*)&As[buf][0] + fb), 16, 0, 0);
    }
#pragma unroll
    for (int s = 0; s < 2; ++s) {
      int fb = (w * 2 + s) * 1024;
      int f = fb + l * 16;
      int row = f >> 6, cb = (f & 63) >> 1;
      __builtin_amdgcn_global_load_lds(
          (g_void*)(Btp + (size_t)(n0 + row) * K + k0 + cb),
          (lds_void*)((char*)&Bs[buf][0] + fb), 16, 0, 0);
    }
  };
  auto compute = [&](int buf) {
    s16x8 af[4], bfr[NR];
#pragma unroll
    for (int mi = 0; mi < 4; ++mi)
      af[mi] = *(const s16x8*)(&As[buf][0] + (wm * 64 + mi * 16 + lr) * 32 + lg * 8);
#pragma unroll
    for (int ni = 0; ni < NR; ++ni)
      bfr[ni] = *(const s16x8*)(&Bs[buf][0] + (wcol + ni * 16 + lr) * 32 + lg * 8);
    __builtin_amdgcn_s_setprio(1);
#pragma unroll
    for (int mi = 0; mi < 4; ++mi)
#pragma unroll
      for (int ni = 0; ni < NR; ++ni)
        acc[mi][ni] = __builtin_amdgcn_mfma_f32_16x16x32_bf16(af[mi], bfr[ni], acc[mi][ni], 0, 0, 0);
    __builtin_amdgcn_s_setprio(0);
  };

  if constexpr (NBUF == 4) {
    // 4-buffer, 2 K-steps per barrier (NT even)
    stage(0, 0);
    stage(1, 1);
    __syncthreads();
    for (int t = 0; t < NT; t += 2) {
      if (t + 2 < NT) {
        stage(t + 2, (t + 2) & 3);
        stage(t + 3, (t + 3) & 3);
      }
      compute(t & 3);
      compute((t + 1) & 3);
      __syncthreads();
    }
  } else {
    stage(0, 0);
    __syncthreads();
    int cur = 0;
    for (int t = 0; t < NT; ++t) {
      if (t + 1 < NT) stage(t + 1, cur ^ 1);
      compute(cur);
      __syncthreads();
      cur ^= 1;
    }
  }

#pragma unroll
  for (int mi = 0; mi < 4; ++mi) {
#pragma unroll
    for (int ni = 0; ni < NR; ++ni) {
      int row = m0 + wm * 64 + mi * 16 + lg * 4;
      int col = n0 + wcol + ni * 16 + lr;
      f32x4 v = acc[mi][ni];
      if constexpr (OMODE == 0) {
        float bv = U.bias ? U.bias[col] : 0.f;
        float* C = (float*)U.Cv;
#pragma unroll
        for (int r = 0; r < 4; ++r)
          C[(size_t)(row + r) * N + col] = v[r] + bv;
      } else if constexpr (OMODE == 3) {
        float bv = U.bias[col];
        if (col < 2048) {
          ushort* dst = (col < DIM) ? U.qo : U.ko;
          float sc = (col < DIM) ? QSCALE : 1.f;
          int c = col & (DIM - 1);
#pragma unroll
          for (int r = 0; r < 4; ++r)
            dst[(size_t)(row + r) * DIM + c] = f2bf((v[r] + bv) * sc);
        } else {
          int c = col - 2048;
          ushort4 o4 = make_ushort4(f2bf(v[0] + bv), f2bf(v[1] + bv),
                                    f2bf(v[2] + bv), f2bf(v[3] + bv));
          *(ushort4*)&U.vo[((size_t)((row >> 9) << 10) + c) * T + (row & 511)] = o4;
        }
      } else if constexpr (OMODE == 4) {
        float bv = U.bias[col];
        float gv = U.gg[col], bev = U.bb[col];
#pragma unroll
        for (int r = 0; r < 4; ++r) {
          float val = v[r] + bv + U.xres[(size_t)(row + r) * DIM + col];
          float sq = val * val;
          sq += __shfl_xor(sq, 1);
          sq += __shfl_xor(sq, 2);
          float invn = rsqrtf(sq + 1e-6f);
          float res = gv * (val * invn) + bev;
          U.xres[(size_t)(row + r) * DIM + col] = res;
          U.xbf[(size_t)(row + r) * DIM + col] = f2bf(res);
          if (U.realout) {
            float rsq = res * res;
            rsq += __shfl_xor(rsq, 1);
            rsq += __shfl_xor(rsq, 2);
            if ((col & 3) == 0)
              U.realout[(size_t)(row + r) * D + (col >> 2)] = f2bf(sqrtf(rsq));
          }
        }
      } else if constexpr (OMODE == 5) {  // modrelu
        float bv = U.bias[col];
        float mb = U.modb[col >> 2];
        ushort* C = (ushort*)U.Cv;
#pragma unroll
        for (int r = 0; r < 4; ++r) {
          float val = v[r] + bv;
          float sq = val * val;
          sq += __shfl_xor(sq, 1);
          sq += __shfl_xor(sq, 2);
          float norm = sqrtf(sq);
          float scale = fmaxf(norm + mb, 0.f) / (norm + 1e-6f);
          C[(size_t)(row + r) * N + col] = f2bf(val * scale);
        }
      } else {  // OMODE 6: bf16 K-partial, no bias
        ushort* P = (ushort*)U.Cv + (size_t)split * BT * N;
#pragma unroll
        for (int r = 0; r < 4; ++r)
          P[(size_t)(row + r) * N + col] = f2bf(v[r]);
      }
    }
  }
}

// ---------------------------------------------------------------------------
// split-K merge for FF2: sum 4 bf16 partials + bias + residual -> qnorm.
// One quaternion (4 adjacent cols) per thread: no cross-lane ops.
__global__ __launch_bounds__(256) void ff2_merge_kernel(
    const ushort* __restrict__ P, const float* __restrict__ bias,
    float* __restrict__ xres, ushort* __restrict__ xbf,
    const float* __restrict__ gg, const float* __restrict__ bb,
    ushort* __restrict__ realo) {
  int idx = blockIdx.x * 256 + threadIdx.x;   // BT*256 threads
  int row = idx >> 8;
  int c4 = (idx & 255) << 2;
  size_t base = (size_t)row * DIM + c4;
  float a0 = 0.f, a1 = 0.f, a2 = 0.f, a3 = 0.f;
#pragma unroll
  for (int sp = 0; sp < 4; ++sp) {
    ushort4 p = *(const ushort4*)(P + (size_t)sp * BT * DIM + base);
    a0 += bf2f(p.x); a1 += bf2f(p.y); a2 += bf2f(p.z); a3 += bf2f(p.w);
  }
  float4 xv = *(float4*)(xres + base);
  float v0 = a0 + bias[c4 + 0] + xv.x;
  float v1 = a1 + bias[c4 + 1] + xv.y;
  float v2 = a2 + bias[c4 + 2] + xv.z;
  float v3 = a3 + bias[c4 + 3] + xv.w;
  float invn = rsqrtf(v0 * v0 + v1 * v1 + v2 * v2 + v3 * v3 + 1e-6f);
  float r0 = gg[c4 + 0] * (v0 * invn) + bb[c4 + 0];
  float r1 = gg[c4 + 1] * (v1 * invn) + bb[c4 + 1];
  float r2 = gg[c4 + 2] * (v2 * invn) + bb[c4 + 2];
  float r3 = gg[c4 + 3] * (v3 * invn) + bb[c4 + 3];
  *(float4*)(xres + base) = make_float4(r0, r1, r2, r3);
  *(ushort4*)(xbf + base) = make_ushort4(f2bf(r0), f2bf(r1), f2bf(r2), f2bf(r3));
  if (realo)
    realo[(size_t)row * D + (c4 >> 2)] =
        f2bf(sqrtf(r0 * r0 + r1 * r1 + r2 * r2 + r3 * r3));
}

// ---------------------------------------------------------------------------
// fused flash attention, head-dim 128. grid (T/64, NH, B*npair), 4 waves.
// Q pre-scaled in QKV epilogue. Defer-max (THR=8) skips O-rescale.
__global__ __launch_bounds__(256) void fused_attn_kernel(
    const ushort* __restrict__ qb, const ushort* __restrict__ kb,
    const ushort* __restrict__ vT, ushort* __restrict__ outA,
    int c0, int c1) {
  __shared__ ushort Ks[2][64 * 128];
  __shared__ ushort Vs[2][128 * 64];
  __shared__ ushort Pst[4][1024];
  const int tid = threadIdx.x;
  const int wq = tid >> 6, l = tid & 63;
  const int lr = l & 15, lg = l >> 4;
  const int h = blockIdx.y;
  const int u = blockIdx.z >> 2, b = blockIdx.z & 3;
  const size_t uoff = (size_t)u * ((size_t)BT * DIM);
  const int causal = u ? c1 : c0;
  const int q0 = blockIdx.x * 64 + wq * 16;
  const size_t bT = (size_t)b * T;
  const int hc = h * 128;
  const size_t vrow0 = (size_t)(b * NH + h) * 128;
  const ushort* qbu = qb + uoff;
  const ushort* kbu = kb + uoff;
  const ushort* vTu = vT + uoff;
  ushort* outu = outA + uoff;
  s16x8 qf[4];
#pragma unroll
  for (int ks = 0; ks < 4; ++ks)
    qf[ks] = *(const s16x8*)(qbu + (bT + q0 + lr) * DIM + hc + ks * 32 + lg * 8);
  f32x4 O[8] = {};
  float m[4] = {-3e38f, -3e38f, -3e38f, -3e38f};
  float lac[4] = {0.f, 0.f, 0.f, 0.f};
  const int kend = causal ? (blockIdx.x + 1) * 64 : T;
  const int ntile = kend >> 6;

  auto stageKV = [&](int tile, int buf) {
    int kv0 = tile << 6;
#pragma unroll
    for (int s = 0; s < 4; ++s) {
      int f = s * 4096 + tid * 16;
      int row = f >> 8, g = (f >> 4) & 15;
      int gs = g ^ (row & 7);
      __builtin_amdgcn_global_load_lds(
          (g_void*)(kbu + (bT + kv0 + row) * DIM + hc + gs * 8),
          (lds_void*)((char*)&Ks[buf][0] + f), 16, 0, 0);
    }
#pragma unroll
    for (int s = 0; s < 4; ++s) {
      int f = s * 4096 + tid * 16;
      int row = f >> 7, g = (f >> 4) & 7;
      int gs = g ^ (row & 7);
      __builtin_amdgcn_global_load_lds(
          (g_void*)(vTu + (vrow0 + row) * T + kv0 + gs * 8),
          (lds_void*)((char*)&Vs[buf][0] + f), 16, 0, 0);
    }
  };

  stageKV(0, 0);
  __syncthreads();
  int cur = 0;
  for (int tile = 0; tile < ntile; ++tile) {
    const int kv0 = tile << 6;
    if (tile + 1 < ntile) stageKV(tile + 1, cur ^ 1);
    f32x4 s[4] = {};
#pragma unroll
    for (int ks = 0; ks < 4; ++ks) {
      s16x8 kf[4];
#pragma unroll
      for (int ni = 0; ni < 4; ++ni) {
        int row = ni * 16 + lr;
        int g = (ks * 4 + lg) ^ (row & 7);
        kf[ni] = *(const s16x8*)(&Ks[cur][0] + row * 128 + g * 8);
      }
#pragma unroll
      for (int ni = 0; ni < 4; ++ni)
        s[ni] = __builtin_amdgcn_mfma_f32_16x16x32_bf16(qf[ks], kf[ni], s[ni], 0, 0, 0);
    }
    const bool domask = causal && (kv0 + 63 > q0);
#pragma unroll
    for (int r = 0; r < 4; ++r) {
      const int qrow = q0 + lg * 4 + r;
      float mx = -3e38f;
#pragma unroll
      for (int ni = 0; ni < 4; ++ni) {
        float v = s[ni][r];
        if (domask && (kv0 + ni * 16 + lr > qrow)) v = -3e38f;
        s[ni][r] = v;
        mx = fmaxf(mx, v);
      }
#pragma unroll
      for (int dd = 1; dd < 16; dd <<= 1) mx = fmaxf(mx, __shfl_xor(mx, dd));
      if (__ballot(mx > m[r] + 8.f)) {
        float mn = fmaxf(m[r], mx);
        float alpha = __expf(m[r] - mn);
        m[r] = mn;
        lac[r] *= alpha;
#pragma unroll
        for (int dni = 0; dni < 8; ++dni) O[dni][r] *= alpha;
      }
      float ps = 0.f;
#pragma unroll
      for (int ni = 0; ni < 4; ++ni) {
        float p = __expf(s[ni][r] - m[r]);
        s[ni][r] = p;
        ps += p;
      }
#pragma unroll
      for (int dd = 1; dd < 16; dd <<= 1) ps += __shfl_xor(ps, dd);
      lac[r] += ps;
      const int qloc = lg * 4 + r;
      const int sw = (qloc & 7) << 3;
#pragma unroll
      for (int ni = 0; ni < 4; ++ni)
        Pst[wq][qloc * 64 + ((ni * 16 + lr) ^ sw)] = f2bf(s[ni][r]);
    }
    asm volatile("s_waitcnt lgkmcnt(0)" ::: "memory");
    __builtin_amdgcn_sched_barrier(0);
#pragma unroll
    for (int ks2 = 0; ks2 < 2; ++ks2) {
      s16x8 pa = *(const s16x8*)&Pst[wq][lr * 64 + ((ks2 * 32 + lg * 8) ^ ((lr & 7) << 3))];
#pragma unroll
      for (int dni = 0; dni < 8; ++dni) {
        int row = dni * 16 + lr;
        int g = (ks2 * 4 + lg) ^ (row & 7);
        s16x8 vf = *(const s16x8*)(&Vs[cur][0] + row * 64 + g * 8);
        O[dni] = __builtin_amdgcn_mfma_f32_16x16x32_bf16(pa, vf, O[dni], 0, 0, 0);
      }
    }
    __syncthreads();
    cur ^= 1;
  }
#pragma unroll
  for (int r = 0; r < 4; ++r) {
    float inv = 1.f / lac[r];
    const size_t row = bT + q0 + lg * 4 + r;
#pragma unroll
    for (int dni = 0; dni < 8; ++dni)
      outu[row * DIM + hc + dni * 16 + lr] = f2bf(O[dni][r] * inv);
  }
}

// ---------------------------------------------------------------------------
extern "C" void kernel_launch(void* const* d_in, const int* in_sizes, int n_in,
                              void* d_out, int out_size, void* d_ws, size_t ws_size,
                              hipStream_t stream) {
  const int*   src        = (const int*)d_in[0];
  const int*   tgt        = (const int*)d_in[1];
  const float* emb        = (const float*)d_in[3];
  const float* enc_attn_W = (const float*)d_in[4];
  const float* enc_attn_b = (const float*)d_in[5];
  const float* enc_norm_g = (const float*)d_in[6];
  const float* enc_norm_b = (const float*)d_in[7];
  const float* enc_ff_W1  = (const float*)d_in[8];
  const float* enc_ff_b1  = (const float*)d_in[9];
  const float* enc_ff_mod = (const float*)d_in[10];
  const float* enc_ff_W2  = (const float*)d_in[11];
  const float* enc_ff_b2  = (const float*)d_in[12];
  const float* dec_sa_W   = (const float*)d_in[13];
  const float* dec_sa_b   = (const float*)d_in[14];
  const float* dec_ca_W   = (const float*)d_in[15];
  const float* dec_ca_b   = (const float*)d_in[16];
  const float* dec_norm_g = (const float*)d_in[17];
  const float* dec_norm_b = (const float*)d_in[18];
  const float* dec_ff_W1  = (const float*)d_in[19];
  const float* dec_ff_b1  = (const float*)d_in[20];
  const float* dec_ff_mod = (const float*)d_in[21];
  const float* dec_ff_W2  = (const float*)d_in[22];
  const float* dec_ff_b2  = (const float*)d_in[23];
  const float* fc_W       = (const float*)d_in[24];
  const float* fc_b       = (const float*)d_in[25];
  float* out = (float*)d_out;

  const size_t USZ = (size_t)BT * DIM;
  float* ws    = (float*)d_ws;
  float* xsrc  = ws;
  float* xtgt  = xsrc + USZ;
  ushort* xbf_src = (ushort*)(xtgt + USZ);
  ushort* xbf_tgt = xbf_src + USZ;
  ushort* aobf    = xbf_tgt + USZ;      // 2 units
  ushort* qb      = aobf + 2 * USZ;     // 2 units
  ushort* kb      = qb + 2 * USZ;       // 2 units
  ushort* vTb     = kb + 2 * USZ;       // 2 units
  ushort* hbf     = vTb + 2 * USZ;      // BT*4096
  ushort* realbf  = hbf + (size_t)BT * H * 4;
  ushort* WA      = realbf + (size_t)BT * D;      // 24 * WSTEP
  ushort* WF      = WA + (size_t)6 * 4 * WSTEP;   // 8 * FFW
  ushort* Wfc     = WF + (size_t)4 * 2 * FFW;     // V*D
  ushort* Pff     = Wfc + (size_t)V * D;          // 4 * BT * DIM (split-K partials)

  mega_expand_kernel<<<(MEGA_TOT + 255) / 256, 256, 0, stream>>>(
      enc_attn_W, dec_sa_W, dec_ca_W,
      enc_ff_W1, enc_ff_W2, dec_ff_W1, dec_ff_W2, fc_W, WA, WF, Wfc,
      src, tgt, emb, xsrc, xbf_src, xtgt, xbf_tgt);

  GP Z{};

  auto mkQKV = [&](const ushort* Abf, const ushort* Wu, const float* bb, int u) {
    GP g = Z;
    g.A = Abf; g.Bt = Wu; g.bias = bb;
    g.qo = qb + u * USZ; g.ko = kb + u * USZ; g.vo = vTb + u * USZ;
    return g;
  };
  auto mkOP = [&](int u, const ushort* Wu3, const float* bb, float* xres,
                  ushort* xbf, const float* gg, const float* nb, ushort* realo) {
    GP g = Z;
    g.A = aobf + u * USZ; g.Bt = Wu3; g.bias = bb;
    g.xres = xres; g.xbf = xbf; g.gg = gg; g.bb = nb; g.realout = realo;
    return g;
  };

  auto qkv1 = [&](GP g) {
    gemm_bf16_kernel<3, 128, 2><<<384, 256, 0, stream>>>(g, g, 1, 1, 3 * DIM, DIM);
  };
  auto qkv2 = [&](GP g0, GP g1) {
    gemm_bf16_kernel<3, 128, 2><<<768, 256, 0, stream>>>(g0, g1, 2, 1, 3 * DIM, DIM);
  };
  auto op1 = [&](GP g) {
    gemm_bf16_kernel<4, 64, 4><<<256, 256, 0, stream>>>(g, g, 1, 1, DIM, DIM);
  };
  auto op2 = [&](GP g0, GP g1) {
    gemm_bf16_kernel<4, 64, 4><<<512, 256, 0, stream>>>(g0, g1, 2, 1, DIM, DIM);
  };
  auto attn1 = [&](int causal) {
    fused_attn_kernel<<<dim3(T / 64, NH, B), 256, 0, stream>>>(
        qb, kb, vTb, aobf, causal, causal);
  };
  auto ffpair = [&](const ushort* xbf, int layer, const float* b1,
                    const float* mod, const float* b2, float* xres,
                    ushort* xbfo, const float* gg, const float* nb,
                    ushort* realo) {
    const ushort* Wf = WF + (size_t)layer * 2 * FFW;
    GP g1 = Z;
    g1.A = xbf; g1.Bt = Wf; g1.bias = b1; g1.Cv = hbf; g1.modb = mod;
    gemm_bf16_kernel<5, 128, 2><<<512, 256, 0, stream>>>(g1, g1, 1, 1, 4 * H, DIM);
    // FF2: split-K x4 -> bf16 partials, then merge+qnorm
    GP g2 = Z;
    g2.A = hbf; g2.Bt = Wf + FFW; g2.Cv = Pff;
    gemm_bf16_kernel<6, 64, 2><<<1024, 256, 0, stream>>>(g2, g2, 1, 4, DIM, 4 * H);
    ff2_merge_kernel<<<BT, 256, 0, stream>>>(Pff, b2, xres, xbfo, gg, nb, realo);
  };

  // ---- enc.l0 ∥ dec.sa0 : merged QKV / attn / out-proj
  {
    GP e = mkQKV(xbf_src, WA + (size_t)(0 * 4) * WSTEP, enc_attn_b, 0);
    GP d = mkQKV(xbf_tgt, WA + (size_t)(2 * 4) * WSTEP, dec_sa_b, 1);
    qkv2(e, d);
    fused_attn_kernel<<<dim3(T / 64, NH, 2 * B), 256, 0, stream>>>(
        qb, kb, vTb, aobf, 0, 1);
    GP eo = mkOP(0, WA + (size_t)(0 * 4 + 3) * WSTEP, enc_attn_b + 3 * DIM,
                 xsrc, xbf_src, enc_norm_g, enc_norm_b, nullptr);
    GP dd = mkOP(1, WA + (size_t)(2 * 4 + 3) * WSTEP, dec_sa_b + 3 * DIM,
                 xtgt, xbf_tgt, dec_norm_g, dec_norm_b, nullptr);
    op2(eo, dd);
  }
  ffpair(xbf_src, 0, enc_ff_b1, enc_ff_mod, enc_ff_b2, xsrc, xbf_src,
         enc_norm_g + 1 * DIM, enc_norm_b + 1 * DIM, nullptr);
  // ---- enc.l1
  {
    GP e = mkQKV(xbf_src, WA + (size_t)(1 * 4) * WSTEP,
                 enc_attn_b + (size_t)1 * 4 * DIM, 0);
    qkv1(e);
    attn1(0);
    GP eo = mkOP(0, WA + (size_t)(1 * 4 + 3) * WSTEP,
                 enc_attn_b + (size_t)1 * 4 * DIM + 3 * DIM,
                 xsrc, xbf_src, enc_norm_g + 2 * DIM, enc_norm_b + 2 * DIM, nullptr);
    op1(eo);
  }
  ffpair(xbf_src, 1, enc_ff_b1 + (size_t)1 * H * 4, enc_ff_mod + H,
         enc_ff_b2 + DIM, xsrc, xbf_src,
         enc_norm_g + 3 * DIM, enc_norm_b + 3 * DIM, nullptr);

  // ---- decoder layers
  for (int l = 0; l < LD; ++l) {
    if (l > 0) {
      GP d = mkQKV(xbf_tgt, WA + (size_t)((2 + l) * 4) * WSTEP,
                   dec_sa_b + (size_t)l * 4 * DIM, 0);
      qkv1(d);
      attn1(1);
      GP od = mkOP(0, WA + (size_t)((2 + l) * 4 + 3) * WSTEP,
                   dec_sa_b + (size_t)l * 4 * DIM + 3 * DIM,
                   xtgt, xbf_tgt, dec_norm_g + (size_t)(l * 3) * DIM,
                   dec_norm_b + (size_t)(l * 3) * DIM, nullptr);
      op1(od);
    }
    {
      GP g = mkQKV(xbf_tgt, WA + (size_t)((4 + l) * 4) * WSTEP,
                   dec_ca_b + (size_t)l * 4 * DIM, 0);
      g.Aalt = xbf_src; g.altStart = DIM;
      qkv1(g);
      attn1(0);
      GP og = mkOP(0, WA + (size_t)((4 + l) * 4 + 3) * WSTEP,
                   dec_ca_b + (size_t)l * 4 * DIM + 3 * DIM,
                   xtgt, xbf_tgt, dec_norm_g + (size_t)(l * 3 + 1) * DIM,
                   dec_norm_b + (size_t)(l * 3 + 1) * DIM, nullptr);
      op1(og);
    }
    ffpair(xbf_tgt, 2 + l, dec_ff_b1 + (size_t)l * H * 4,
           dec_ff_mod + (size_t)l * H, dec_ff_b2 + (size_t)l * DIM,
           xtgt, xbf_tgt, dec_norm_g + (size_t)(l * 3 + 2) * DIM,
           dec_norm_b + (size_t)(l * 3 + 2) * DIM,
           (l == LD - 1) ? realbf : nullptr);
  }

  // logits
  {
    GP g = Z;
    g.A = realbf; g.Bt = Wfc; g.bias = fc_b; g.Cv = out;
    gemm_bf16_kernel<0, 128, 2><<<(V / 128) * (BT / 128), 256, 0, stream>>>(
        g, g, 1, 1, V, 256);
  }
}

// Round 13
// 929.975 us; speedup vs baseline: 1.5982x; 1.0341x over previous
//
#include <hip/hip_runtime.h>
#include <math.h>

#define B 4
#define T 512
#define D 256
#define H 1024
#define NH 8
#define V 32000
#define BT (B*T)
#define LE 2
#define LD 2
#define DIM 1024  // expanded width = 4*D

typedef __attribute__((ext_vector_type(8))) short s16x8;
typedef __attribute__((ext_vector_type(4))) float f32x4;
typedef __attribute__((address_space(3))) void lds_void;
typedef const __attribute__((address_space(1))) void g_void;

__device__ __forceinline__ ushort f2bf(float x) {
  uint u = __float_as_uint(x);
  return (ushort)((u + 0x7fffu + ((u >> 16) & 1u)) >> 16);
}
__device__ __forceinline__ float bf2f(ushort u) {
  return __uint_as_float(((uint)u) << 16);
}

#define QSCALE 0.08838834764831845f  // 1/sqrt(128), baked into Q at QKV epilogue

// ---------------------------------------------------------------------------
// ONE launch: all weight expansion + fc convert + BOTH embeds
#define A_CNT  1572864
#define F_CNT  2097152
#define FC_CNT 2048000
#define EMB_CNT (2 * BT * 256)
#define MEGA_TOT (A_CNT + F_CNT + FC_CNT + EMB_CNT)
#define WSTEP  1048576   // DIM*DIM elems
#define FFW    4194304   // 4H*DIM elems

__device__ __forceinline__ void qexpand_write(
    const float* __restrict__ src, ushort* __restrict__ dst,
    int o, int d, int Din, int P) {
  float w0 = src[(size_t)o * Din + d];
  float w1 = src[P + (size_t)o * Din + d];
  float w2 = src[2 * (size_t)P + (size_t)o * Din + d];
  float w3 = src[3 * (size_t)P + (size_t)o * Din + d];
  int K4 = Din * 4;
  size_t rbase = (size_t)(o * 4) * K4 + d * 4;
  *(ushort4*)(dst + rbase)          = make_ushort4(f2bf(w0), f2bf(-w1), f2bf(-w2), f2bf(-w3));
  *(ushort4*)(dst + rbase + K4)     = make_ushort4(f2bf(w1), f2bf(w0),  f2bf(w3),  f2bf(-w2));
  *(ushort4*)(dst + rbase + 2 * K4) = make_ushort4(f2bf(w2), f2bf(-w3), f2bf(w0),  f2bf(w1));
  *(ushort4*)(dst + rbase + 3 * K4) = make_ushort4(f2bf(w3), f2bf(w2),  f2bf(-w1), f2bf(w0));
}

__global__ __launch_bounds__(256) void mega_expand_kernel(
    const float* __restrict__ encA, const float* __restrict__ decSA,
    const float* __restrict__ decCA,
    const float* __restrict__ eW1, const float* __restrict__ eW2,
    const float* __restrict__ dW1, const float* __restrict__ dW2,
    const float* __restrict__ fcW,
    ushort* __restrict__ WA, ushort* __restrict__ WF, ushort* __restrict__ Wfc,
    const int* __restrict__ srcIds, const int* __restrict__ tgtIds,
    const float* __restrict__ emb,
    float* __restrict__ xsrc, ushort* __restrict__ xbfs,
    float* __restrict__ xtgt, ushort* __restrict__ xbft) {
  int gid = blockIdx.x * 256 + threadIdx.x;
  if (gid < A_CNT) {
    int u = gid >> 18;
    int p = (gid >> 16) & 3;
    int rem = gid & 65535;
    int o = rem >> 8, d = rem & 255;
    const float* base = (u < 2) ? encA + (size_t)u * 1048576
                      : (u < 4) ? decSA + (size_t)(u - 2) * 1048576
                                : decCA + (size_t)(u - 4) * 1048576;
    qexpand_write(base + (size_t)p * 262144,
                  WA + ((size_t)u * 4 + p) * WSTEP, o, d, 256, 65536);
  } else if (gid < A_CNT + F_CNT) {
    int idx = gid - A_CNT;
    int layer = idx >> 19;
    int w12 = (idx >> 18) & 1;
    int rem = idx & 262143;
    const float* w1b = (layer < 2) ? eW1 + (size_t)layer * 1048576
                                   : dW1 + (size_t)(layer - 2) * 1048576;
    const float* w2b = (layer < 2) ? eW2 + (size_t)layer * 1048576
                                   : dW2 + (size_t)(layer - 2) * 1048576;
    ushort* dst = WF + (size_t)layer * 2 * FFW + (size_t)w12 * FFW;
    if (w12 == 0) {
      int o = rem >> 8, d = rem & 255;
      qexpand_write(w1b, dst, o, d, 256, 262144);
    } else {
      int o = rem >> 10, d = rem & 1023;
      qexpand_write(w2b, dst, o, d, 1024, 262144);
    }
  } else if (gid < A_CNT + F_CNT + FC_CNT) {
    int idx = gid - A_CNT - F_CNT;
    float4 v = ((const float4*)fcW)[idx];
    ((ushort4*)Wfc)[idx] = make_ushort4(f2bf(v.x), f2bf(v.y), f2bf(v.z), f2bf(v.w));
  } else if (gid < MEGA_TOT) {
    int idx = gid - A_CNT - F_CNT - FC_CNT;
    int g = idx >> 8, d = idx & 255;
    int isTgt = g >= BT;
    int bt = isTgt ? g - BT : g;
    int id = isTgt ? tgtIds[bt] : srcIds[bt];
    float* out = isTgt ? xtgt : xsrc;
    ushort* outbf = isTgt ? xbft : xbfs;
    int t = bt % T;
    size_t VD = (size_t)V * D;
    float scale = powf(10000.f, -(float)d / (float)D);
    float r = emb[(size_t)id * D + d];
    float i = emb[VD + (size_t)id * D + d] * scale;
    float j = emb[2 * VD + (size_t)id * D + d] * scale;
    float k = emb[3 * VD + (size_t)id * D + d] * scale;
    float n = sqrtf(r * r + i * i + j * j + k * k + 1e-6f);
    float ang;
    if (d < D / 2) {
      float inv = powf(10000.f, -(float)(2 * d) / (float)D);
      ang = sinf((float)t * inv);
    } else {
      float inv = powf(10000.f, -(float)(2 * (d - D / 2)) / (float)D);
      ang = cosf((float)t * inv);
    }
    float s = ang / n;
    size_t base = (size_t)bt * DIM + d * 4;
    float4 q = make_float4(r * s, i * s, j * s, k * s);
    *(float4*)(out + base) = q;
    *(ushort4*)(outbf + base) = make_ushort4(f2bf(q.x), f2bf(q.y), f2bf(q.z), f2bf(q.w));
  }
}

// ---------------------------------------------------------------------------
// Unit-routed GEMM params
struct GP {
  const ushort* A; const ushort* Aalt; int altStart;
  const ushort* Bt; const float* bias; void* Cv;
  ushort* qo; ushort* ko; ushort* vo;
  const float* modb;
};

// ---------------------------------------------------------------------------
// 4-wave GEMM core. Routing: nunits independent GEMMs and/or nsplit K-slices
// per dispatch (split-K partials are deterministic: separate buffers).
// OMODE 0: f32+bias. OMODE 3: QKV epilogue (Q pre-scaled).
// OMODE 5: +modrelu->bf16. OMODE 6: bf16 K-partial (split-K).
template <int OMODE, int TM>
__global__ __launch_bounds__(256, 4) void gemm_bf16_kernel(
    GP u0, GP u1, int nunits, int nsplit, int N, int K) {
  __shared__ ushort As[2][TM * 32];
  __shared__ ushort Bs[2][128 * 32];
  const int tid = threadIdx.x;
  const int w = tid >> 6, l = tid & 63;
  const int nwg = gridDim.x;
  const int qq = nwg >> 3, rr = nwg & 7;
  const int xcd = blockIdx.x & 7, pos = blockIdx.x >> 3;
  const int wg = (xcd < rr ? xcd * (qq + 1) : rr * (qq + 1) + (xcd - rr) * qq) + pos;
  const int uwg = nwg / (nunits * nsplit);
  const int idx = wg / uwg;
  const int unit = idx / nsplit;
  const int split = idx % nsplit;
  const int wgl = wg % uwg;
  GP U = unit ? u1 : u0;
  const int Ksub = K / nsplit;
  const int kbase = split * Ksub;
  const int nbx = N >> 7;
  const int nby = uwg / nbx;
  const int m0 = (wgl % nby) * TM, n0 = (wgl / nby) * 128;
  const ushort* Ap = (U.altStart && n0 >= U.altStart) ? U.Aalt : U.A;
  const ushort* Btp = U.Bt;
  const int lr = l & 15, lg = l >> 4;
  constexpr int NR = (TM == 128) ? 4 : 2;
  const int wm = (TM == 128) ? (w >> 1) : 0;
  const int wn = (TM == 128) ? (w & 1) : w;
  const int wcol = wn * (NR * 16);
  f32x4 acc[4][NR] = {};
  const int NT = Ksub >> 5;

  auto stage = [&](int t, int buf) {
    int k0 = kbase + (t << 5);
#pragma unroll
    for (int s = 0; s < TM / 64; ++s) {
      int fb = (w * (TM / 64) + s) * 1024;
      int f = fb + l * 16;
      int row = f >> 6, cb = (f & 63) >> 1;
      __builtin_amdgcn_global_load_lds(
          (g_void*)(Ap + (size_t)(m0 + row) * K + k0 + cb),
          (lds_void*)((char*)&As[buf][0] + fb), 16, 0, 0);
    }
#pragma unroll
    for (int s = 0; s < 2; ++s) {
      int fb = (w * 2 + s) * 1024;
      int f = fb + l * 16;
      int row = f >> 6, cb = (f & 63) >> 1;
      __builtin_amdgcn_global_load_lds(
          (g_void*)(Btp + (size_t)(n0 + row) * K + k0 + cb),
          (lds_void*)((char*)&Bs[buf][0] + fb), 16, 0, 0);
    }
  };
  auto compute = [&](int buf) {
    s16x8 af[4], bfr[NR];
#pragma unroll
    for (int mi = 0; mi < 4; ++mi)
      af[mi] = *(const s16x8*)(&As[buf][0] + (wm * 64 + mi * 16 + lr) * 32 + lg * 8);
#pragma unroll
    for (int ni = 0; ni < NR; ++ni)
      bfr[ni] = *(const s16x8*)(&Bs[buf][0] + (wcol + ni * 16 + lr) * 32 + lg * 8);
    __builtin_amdgcn_s_setprio(1);
#pragma unroll
    for (int mi = 0; mi < 4; ++mi)
#pragma unroll
      for (int ni = 0; ni < NR; ++ni)
        acc[mi][ni] = __builtin_amdgcn_mfma_f32_16x16x32_bf16(af[mi], bfr[ni], acc[mi][ni], 0, 0, 0);
    __builtin_amdgcn_s_setprio(0);
  };

  stage(0, 0);
  __syncthreads();
  int cur = 0;
  for (int t = 0; t < NT; ++t) {
    if (t + 1 < NT) stage(t + 1, cur ^ 1);
    compute(cur);
    __syncthreads();
    cur ^= 1;
  }

#pragma unroll
  for (int mi = 0; mi < 4; ++mi) {
#pragma unroll
    for (int ni = 0; ni < NR; ++ni) {
      int row = m0 + wm * 64 + mi * 16 + lg * 4;
      int col = n0 + wcol + ni * 16 + lr;
      f32x4 v = acc[mi][ni];
      if constexpr (OMODE == 0) {
        float bv = U.bias ? U.bias[col] : 0.f;
        float* C = (float*)U.Cv;
#pragma unroll
        for (int r = 0; r < 4; ++r)
          C[(size_t)(row + r) * N + col] = v[r] + bv;
      } else if constexpr (OMODE == 3) {
        float bv = U.bias[col];
        if (col < 2048) {
          ushort* dst = (col < DIM) ? U.qo : U.ko;
          float sc = (col < DIM) ? QSCALE : 1.f;
          int c = col & (DIM - 1);
#pragma unroll
          for (int r = 0; r < 4; ++r)
            dst[(size_t)(row + r) * DIM + c] = f2bf((v[r] + bv) * sc);
        } else {
          int c = col - 2048;
          ushort4 o4 = make_ushort4(f2bf(v[0] + bv), f2bf(v[1] + bv),
                                    f2bf(v[2] + bv), f2bf(v[3] + bv));
          *(ushort4*)&U.vo[((size_t)((row >> 9) << 10) + c) * T + (row & 511)] = o4;
        }
      } else if constexpr (OMODE == 5) {  // modrelu
        float bv = U.bias[col];
        float mb = U.modb[col >> 2];
        ushort* C = (ushort*)U.Cv;
#pragma unroll
        for (int r = 0; r < 4; ++r) {
          float val = v[r] + bv;
          float sq = val * val;
          sq += __shfl_xor(sq, 1);
          sq += __shfl_xor(sq, 2);
          float norm = sqrtf(sq);
          float scale = fmaxf(norm + mb, 0.f) / (norm + 1e-6f);
          C[(size_t)(row + r) * N + col] = f2bf(val * scale);
        }
      } else {  // OMODE 6: bf16 K-partial, no bias
        ushort* P = (ushort*)U.Cv + (size_t)split * BT * N;
#pragma unroll
        for (int r = 0; r < 4; ++r)
          P[(size_t)(row + r) * N + col] = f2bf(v[r]);
      }
    }
  }
}

// ---------------------------------------------------------------------------
// split-K merge (shared by OP and FF2): sum 4 bf16 partials + bias + residual
// -> qnorm (-> optional to_real). One quaternion per thread, no cross-lane.
struct MP {
  const ushort* P; const float* bias;
  float* xres; ushort* xbf;
  const float* gg; const float* bb; ushort* realo;
};

__global__ __launch_bounds__(256) void merge_qnorm_kernel(MP m0, MP m1) {
  int blk = blockIdx.x;
  MP M = (blk >= BT) ? m1 : m0;
  int row = (blk >= BT) ? blk - BT : blk;
  int c4 = threadIdx.x << 2;
  size_t base = (size_t)row * DIM + c4;
  float a0 = 0.f, a1 = 0.f, a2 = 0.f, a3 = 0.f;
#pragma unroll
  for (int sp = 0; sp < 4; ++sp) {
    ushort4 p = *(const ushort4*)(M.P + (size_t)sp * BT * DIM + base);
    a0 += bf2f(p.x); a1 += bf2f(p.y); a2 += bf2f(p.z); a3 += bf2f(p.w);
  }
  float4 xv = *(float4*)(M.xres + base);
  float v0 = a0 + M.bias[c4 + 0] + xv.x;
  float v1 = a1 + M.bias[c4 + 1] + xv.y;
  float v2 = a2 + M.bias[c4 + 2] + xv.z;
  float v3 = a3 + M.bias[c4 + 3] + xv.w;
  float invn = rsqrtf(v0 * v0 + v1 * v1 + v2 * v2 + v3 * v3 + 1e-6f);
  float r0 = M.gg[c4 + 0] * (v0 * invn) + M.bb[c4 + 0];
  float r1 = M.gg[c4 + 1] * (v1 * invn) + M.bb[c4 + 1];
  float r2 = M.gg[c4 + 2] * (v2 * invn) + M.bb[c4 + 2];
  float r3 = M.gg[c4 + 3] * (v3 * invn) + M.bb[c4 + 3];
  *(float4*)(M.xres + base) = make_float4(r0, r1, r2, r3);
  *(ushort4*)(M.xbf + base) = make_ushort4(f2bf(r0), f2bf(r1), f2bf(r2), f2bf(r3));
  if (M.realo)
    M.realo[(size_t)row * D + (c4 >> 2)] =
        f2bf(sqrtf(r0 * r0 + r1 * r1 + r2 * r2 + r3 * r3));
}

// ---------------------------------------------------------------------------
// fused flash attention, head-dim 128. grid (T/64, NH, B*npair), 4 waves.
// Q pre-scaled in QKV epilogue. Defer-max (THR=8) skips O-rescale.
__global__ __launch_bounds__(256) void fused_attn_kernel(
    const ushort* __restrict__ qb, const ushort* __restrict__ kb,
    const ushort* __restrict__ vT, ushort* __restrict__ outA,
    int c0, int c1) {
  __shared__ ushort Ks[2][64 * 128];
  __shared__ ushort Vs[2][128 * 64];
  __shared__ ushort Pst[4][1024];
  const int tid = threadIdx.x;
  const int wq = tid >> 6, l = tid & 63;
  const int lr = l & 15, lg = l >> 4;
  const int h = blockIdx.y;
  const int u = blockIdx.z >> 2, b = blockIdx.z & 3;
  const size_t uoff = (size_t)u * ((size_t)BT * DIM);
  const int causal = u ? c1 : c0;
  const int q0 = blockIdx.x * 64 + wq * 16;
  const size_t bT = (size_t)b * T;
  const int hc = h * 128;
  const size_t vrow0 = (size_t)(b * NH + h) * 128;
  const ushort* qbu = qb + uoff;
  const ushort* kbu = kb + uoff;
  const ushort* vTu = vT + uoff;
  ushort* outu = outA + uoff;
  s16x8 qf[4];
#pragma unroll
  for (int ks = 0; ks < 4; ++ks)
    qf[ks] = *(const s16x8*)(qbu + (bT + q0 + lr) * DIM + hc + ks * 32 + lg * 8);
  f32x4 O[8] = {};
  float m[4] = {-3e38f, -3e38f, -3e38f, -3e38f};
  float lac[4] = {0.f, 0.f, 0.f, 0.f};
  const int kend = causal ? (blockIdx.x + 1) * 64 : T;
  const int ntile = kend >> 6;

  auto stageKV = [&](int tile, int buf) {
    int kv0 = tile << 6;
#pragma unroll
    for (int s = 0; s < 4; ++s) {
      int f = s * 4096 + tid * 16;
      int row = f >> 8, g = (f >> 4) & 15;
      int gs = g ^ (row & 7);
      __builtin_amdgcn_global_load_lds(
          (g_void*)(kbu + (bT + kv0 + row) * DIM + hc + gs * 8),
          (lds_void*)((char*)&Ks[buf][0] + f), 16, 0, 0);
    }
#pragma unroll
    for (int s = 0; s < 4; ++s) {
      int f = s * 4096 + tid * 16;
      int row = f >> 7, g = (f >> 4) & 7;
      int gs = g ^ (row & 7);
      __builtin_amdgcn_global_load_lds(
          (g_void*)(vTu + (vrow0 + row) * T + kv0 + gs * 8),
          (lds_void*)((char*)&Vs[buf][0] + f), 16, 0, 0);
    }
  };

  stageKV(0, 0);
  __syncthreads();
  int cur = 0;
  for (int tile = 0; tile < ntile; ++tile) {
    const int kv0 = tile << 6;
    if (tile + 1 < ntile) stageKV(tile + 1, cur ^ 1);
    f32x4 s[4] = {};
#pragma unroll
    for (int ks = 0; ks < 4; ++ks) {
      s16x8 kf[4];
#pragma unroll
      for (int ni = 0; ni < 4; ++ni) {
        int row = ni * 16 + lr;
        int g = (ks * 4 + lg) ^ (row & 7);
        kf[ni] = *(const s16x8*)(&Ks[cur][0] + row * 128 + g * 8);
      }
#pragma unroll
      for (int ni = 0; ni < 4; ++ni)
        s[ni] = __builtin_amdgcn_mfma_f32_16x16x32_bf16(qf[ks], kf[ni], s[ni], 0, 0, 0);
    }
    const bool domask = causal && (kv0 + 63 > q0);
#pragma unroll
    for (int r = 0; r < 4; ++r) {
      const int qrow = q0 + lg * 4 + r;
      float mx = -3e38f;
#pragma unroll
      for (int ni = 0; ni < 4; ++ni) {
        float v = s[ni][r];
        if (domask && (kv0 + ni * 16 + lr > qrow)) v = -3e38f;
        s[ni][r] = v;
        mx = fmaxf(mx, v);
      }
#pragma unroll
      for (int dd = 1; dd < 16; dd <<= 1) mx = fmaxf(mx, __shfl_xor(mx, dd));
      if (__ballot(mx > m[r] + 8.f)) {
        float mn = fmaxf(m[r], mx);
        float alpha = __expf(m[r] - mn);
        m[r] = mn;
        lac[r] *= alpha;
#pragma unroll
        for (int dni = 0; dni < 8; ++dni) O[dni][r] *= alpha;
      }
      float ps = 0.f;
#pragma unroll
      for (int ni = 0; ni < 4; ++ni) {
        float p = __expf(s[ni][r] - m[r]);
        s[ni][r] = p;
        ps += p;
      }
#pragma unroll
      for (int dd = 1; dd < 16; dd <<= 1) ps += __shfl_xor(ps, dd);
      lac[r] += ps;
      const int qloc = lg * 4 + r;
      const int sw = (qloc & 7) << 3;
#pragma unroll
      for (int ni = 0; ni < 4; ++ni)
        Pst[wq][qloc * 64 + ((ni * 16 + lr) ^ sw)] = f2bf(s[ni][r]);
    }
    asm volatile("s_waitcnt lgkmcnt(0)" ::: "memory");
    __builtin_amdgcn_sched_barrier(0);
#pragma unroll
    for (int ks2 = 0; ks2 < 2; ++ks2) {
      s16x8 pa = *(const s16x8*)&Pst[wq][lr * 64 + ((ks2 * 32 + lg * 8) ^ ((lr & 7) << 3))];
#pragma unroll
      for (int dni = 0; dni < 8; ++dni) {
        int row = dni * 16 + lr;
        int g = (ks2 * 4 + lg) ^ (row & 7);
        s16x8 vf = *(const s16x8*)(&Vs[cur][0] + row * 64 + g * 8);
        O[dni] = __builtin_amdgcn_mfma_f32_16x16x32_bf16(pa, vf, O[dni], 0, 0, 0);
      }
    }
    __syncthreads();
    cur ^= 1;
  }
#pragma unroll
  for (int r = 0; r < 4; ++r) {
    float inv = 1.f / lac[r];
    const size_t row = bT + q0 + lg * 4 + r;
#pragma unroll
    for (int dni = 0; dni < 8; ++dni)
      outu[row * DIM + hc + dni * 16 + lr] = f2bf(O[dni][r] * inv);
  }
}

// ---------------------------------------------------------------------------
extern "C" void kernel_launch(void* const* d_in, const int* in_sizes, int n_in,
                              void* d_out, int out_size, void* d_ws, size_t ws_size,
                              hipStream_t stream) {
  const int*   src        = (const int*)d_in[0];
  const int*   tgt        = (const int*)d_in[1];
  const float* emb        = (const float*)d_in[3];
  const float* enc_attn_W = (const float*)d_in[4];
  const float* enc_attn_b = (const float*)d_in[5];
  const float* enc_norm_g = (const float*)d_in[6];
  const float* enc_norm_b = (const float*)d_in[7];
  const float* enc_ff_W1  = (const float*)d_in[8];
  const float* enc_ff_b1  = (const float*)d_in[9];
  const float* enc_ff_mod = (const float*)d_in[10];
  const float* enc_ff_W2  = (const float*)d_in[11];
  const float* enc_ff_b2  = (const float*)d_in[12];
  const float* dec_sa_W   = (const float*)d_in[13];
  const float* dec_sa_b   = (const float*)d_in[14];
  const float* dec_ca_W   = (const float*)d_in[15];
  const float* dec_ca_b   = (const float*)d_in[16];
  const float* dec_norm_g = (const float*)d_in[17];
  const float* dec_norm_b = (const float*)d_in[18];
  const float* dec_ff_W1  = (const float*)d_in[19];
  const float* dec_ff_b1  = (const float*)d_in[20];
  const float* dec_ff_mod = (const float*)d_in[21];
  const float* dec_ff_W2  = (const float*)d_in[22];
  const float* dec_ff_b2  = (const float*)d_in[23];
  const float* fc_W       = (const float*)d_in[24];
  const float* fc_b       = (const float*)d_in[25];
  float* out = (float*)d_out;

  const size_t USZ = (size_t)BT * DIM;
  float* ws    = (float*)d_ws;
  float* xsrc  = ws;
  float* xtgt  = xsrc + USZ;
  ushort* xbf_src = (ushort*)(xtgt + USZ);
  ushort* xbf_tgt = xbf_src + USZ;
  ushort* aobf    = xbf_tgt + USZ;      // 2 units
  ushort* qb      = aobf + 2 * USZ;     // 2 units
  ushort* kb      = qb + 2 * USZ;       // 2 units
  ushort* vTb     = kb + 2 * USZ;       // 2 units
  ushort* hbf     = vTb + 2 * USZ;      // BT*4096
  ushort* realbf  = hbf + (size_t)BT * H * 4;
  ushort* WA      = realbf + (size_t)BT * D;      // 24 * WSTEP
  ushort* WF      = WA + (size_t)6 * 4 * WSTEP;   // 8 * FFW
  ushort* Wfc     = WF + (size_t)4 * 2 * FFW;     // V*D
  ushort* Pff     = Wfc + (size_t)V * D;          // 8 * BT * DIM (split-K partials)

  mega_expand_kernel<<<(MEGA_TOT + 255) / 256, 256, 0, stream>>>(
      enc_attn_W, dec_sa_W, dec_ca_W,
      enc_ff_W1, enc_ff_W2, dec_ff_W1, dec_ff_W2, fc_W, WA, WF, Wfc,
      src, tgt, emb, xsrc, xbf_src, xtgt, xbf_tgt);

  GP Z{};
  MP MZ{};

  auto mkQKV = [&](const ushort* Abf, const ushort* Wu, const float* bb, int u) {
    GP g = Z;
    g.A = Abf; g.Bt = Wu; g.bias = bb;
    g.qo = qb + u * USZ; g.ko = kb + u * USZ; g.vo = vTb + u * USZ;
    return g;
  };
  auto mkMP = [&](const ushort* P, const float* bb, float* xres, ushort* xbf,
                  const float* gg, const float* nb, ushort* realo) {
    MP m = MZ;
    m.P = P; m.bias = bb; m.xres = xres; m.xbf = xbf;
    m.gg = gg; m.bb = nb; m.realo = realo;
    return m;
  };

  auto qkv1 = [&](GP g) {
    gemm_bf16_kernel<3, 128><<<384, 256, 0, stream>>>(g, g, 1, 1, 3 * DIM, DIM);
  };
  auto qkv2 = [&](GP g0, GP g1) {
    gemm_bf16_kernel<3, 128><<<768, 256, 0, stream>>>(g0, g1, 2, 1, 3 * DIM, DIM);
  };
  // OP: split-K x4 partials + merge
  auto op1 = [&](int u, const ushort* Wu3, MP m) {
    GP g = Z;
    g.A = aobf + u * USZ; g.Bt = Wu3; g.Cv = Pff;
    gemm_bf16_kernel<6, 64><<<1024, 256, 0, stream>>>(g, g, 1, 4, DIM, DIM);
    merge_qnorm_kernel<<<BT, 256, 0, stream>>>(m, m);
  };
  auto op2 = [&](const ushort* We3, const ushort* Wd3, MP me, MP md) {
    GP g0 = Z, g1 = Z;
    g0.A = aobf; g0.Bt = We3; g0.Cv = Pff;
    g1.A = aobf + USZ; g1.Bt = Wd3; g1.Cv = Pff + 4 * USZ;
    gemm_bf16_kernel<6, 64><<<2048, 256, 0, stream>>>(g0, g1, 2, 4, DIM, DIM);
    merge_qnorm_kernel<<<2 * BT, 256, 0, stream>>>(me, md);
  };
  auto attn1 = [&](int causal) {
    fused_attn_kernel<<<dim3(T / 64, NH, B), 256, 0, stream>>>(
        qb, kb, vTb, aobf, causal, causal);
  };
  auto ffpair = [&](const ushort* xbf, int layer, const float* b1,
                    const float* mod, const float* b2, float* xres,
                    ushort* xbfo, const float* gg, const float* nb,
                    ushort* realo) {
    const ushort* Wf = WF + (size_t)layer * 2 * FFW;
    GP g1 = Z;
    g1.A = xbf; g1.Bt = Wf; g1.bias = b1; g1.Cv = hbf; g1.modb = mod;
    gemm_bf16_kernel<5, 128><<<512, 256, 0, stream>>>(g1, g1, 1, 1, 4 * H, DIM);
    GP g2 = Z;
    g2.A = hbf; g2.Bt = Wf + FFW; g2.Cv = Pff;
    gemm_bf16_kernel<6, 64><<<1024, 256, 0, stream>>>(g2, g2, 1, 4, DIM, 4 * H);
    MP m = mkMP(Pff, b2, xres, xbfo, gg, nb, realo);
    merge_qnorm_kernel<<<BT, 256, 0, stream>>>(m, m);
  };

  // ---- enc.l0 ∥ dec.sa0 : merged QKV / attn / out-proj
  {
    GP e = mkQKV(xbf_src, WA + (size_t)(0 * 4) * WSTEP, enc_attn_b, 0);
    GP d = mkQKV(xbf_tgt, WA + (size_t)(2 * 4) * WSTEP, dec_sa_b, 1);
    qkv2(e, d);
    fused_attn_kernel<<<dim3(T / 64, NH, 2 * B), 256, 0, stream>>>(
        qb, kb, vTb, aobf, 0, 1);
    MP me = mkMP(Pff, enc_attn_b + 3 * DIM, xsrc, xbf_src,
                 enc_norm_g, enc_norm_b, nullptr);
    MP md = mkMP(Pff + 4 * USZ, dec_sa_b + 3 * DIM, xtgt, xbf_tgt,
                 dec_norm_g, dec_norm_b, nullptr);
    op2(WA + (size_t)(0 * 4 + 3) * WSTEP, WA + (size_t)(2 * 4 + 3) * WSTEP, me, md);
  }
  ffpair(xbf_src, 0, enc_ff_b1, enc_ff_mod, enc_ff_b2, xsrc, xbf_src,
         enc_norm_g + 1 * DIM, enc_norm_b + 1 * DIM, nullptr);
  // ---- enc.l1
  {
    GP e = mkQKV(xbf_src, WA + (size_t)(1 * 4) * WSTEP,
                 enc_attn_b + (size_t)1 * 4 * DIM, 0);
    qkv1(e);
    attn1(0);
    MP me = mkMP(Pff, enc_attn_b + (size_t)1 * 4 * DIM + 3 * DIM, xsrc, xbf_src,
                 enc_norm_g + 2 * DIM, enc_norm_b + 2 * DIM, nullptr);
    op1(0, WA + (size_t)(1 * 4 + 3) * WSTEP, me);
  }
  ffpair(xbf_src, 1, enc_ff_b1 + (size_t)1 * H * 4, enc_ff_mod + H,
         enc_ff_b2 + DIM, xsrc, xbf_src,
         enc_norm_g + 3 * DIM, enc_norm_b + 3 * DIM, nullptr);

  // ---- decoder layers
  for (int l = 0; l < LD; ++l) {
    if (l > 0) {
      GP d = mkQKV(xbf_tgt, WA + (size_t)((2 + l) * 4) * WSTEP,
                   dec_sa_b + (size_t)l * 4 * DIM, 0);
      qkv1(d);
      attn1(1);
      MP md = mkMP(Pff, dec_sa_b + (size_t)l * 4 * DIM + 3 * DIM, xtgt, xbf_tgt,
                   dec_norm_g + (size_t)(l * 3) * DIM,
                   dec_norm_b + (size_t)(l * 3) * DIM, nullptr);
      op1(0, WA + (size_t)((2 + l) * 4 + 3) * WSTEP, md);
    }
    {
      GP g = mkQKV(xbf_tgt, WA + (size_t)((4 + l) * 4) * WSTEP,
                   dec_ca_b + (size_t)l * 4 * DIM, 0);
      g.Aalt = xbf_src; g.altStart = DIM;
      qkv1(g);
      attn1(0);
      MP mg = mkMP(Pff, dec_ca_b + (size_t)l * 4 * DIM + 3 * DIM, xtgt, xbf_tgt,
                   dec_norm_g + (size_t)(l * 3 + 1) * DIM,
                   dec_norm_b + (size_t)(l * 3 + 1) * DIM, nullptr);
      op1(0, WA + (size_t)((4 + l) * 4 + 3) * WSTEP, mg);
    }
    ffpair(xbf_tgt, 2 + l, dec_ff_b1 + (size_t)l * H * 4,
           dec_ff_mod + (size_t)l * H, dec_ff_b2 + (size_t)l * DIM,
           xtgt, xbf_tgt, dec_norm_g + (size_t)(l * 3 + 2) * DIM,
           dec_norm_b + (size_t)(l * 3 + 2) * DIM,
           (l == LD - 1) ? realbf : nullptr);
  }

  // logits
  {
    GP g = Z;
    g.A = realbf; g.Bt = Wfc; g.bias = fc_b; g.Cv = out;
    gemm_bf16_kernel<0, 128><<<(V / 128) * (BT / 128), 256, 0, stream>>>(
        g, g, 1, 1, V, 256);
  }
}